// Round 4
// baseline (2555.159 us; speedup 1.0000x reference)
//
#include <hip/hip_runtime.h>

#define N0 100000
#define N1 50000
#define N2 25000
#define E0 500000
#define E1 250000
#define N_TOT (3 * N1 + 3 * N2)
#define NE_ALL (3 * E0 + 3 * E1)
#define NB_SCAN ((N_TOT + 1023) / 1024)

typedef __attribute__((ext_vector_type(8))) short short8;
typedef __attribute__((ext_vector_type(4))) float f32x4;
typedef unsigned short ushort_t;
typedef unsigned int uint_t;

static __device__ __forceinline__ float lrelu(float x, float s) {
    return x >= 0.f ? x : s * x;
}

static __device__ __forceinline__ ushort_t f2bf(float f) {
    union { float f; uint_t u; } v; v.f = f;
    uint_t r = v.u + 0x7FFFu + ((v.u >> 16) & 1u);
    return (ushort_t)(r >> 16);
}

static __device__ __forceinline__ uint_t cvt2(float lo, float hi) {
    uint_t r;
    asm("v_cvt_pk_bf16_f32 %0, %1, %2" : "=v"(r) : "v"(lo), "v"(hi));
    return r;
}

// ================= MFMA GEMM =================
// Block: 256 thr = 4 waves; tile 128 rows x 128 cols (grid.y = col panel).
// A: f32 global (PLANES interleaved virtual rows: row r -> plane r%P, node r/P),
//    converted to bf16 in-reg. B: bf16 panel [col][k] staged to LDS (XOR swizzle).
// Epilogue: +bias, lrelu(slope), col-split routing to O1/O2 (f32).
template <int PLANES>
__global__ __launch_bounds__(256) void gemm_bf16(
    const float* __restrict__ A0, const float* __restrict__ A1,
    const float* __restrict__ A2, const float* __restrict__ A3,
    int nodes, const ushort_t* __restrict__ Bt, int cols,
    const float* __restrict__ biasA, const float* __restrict__ biasB,
    int colsplit, float slopeA, float slopeB,
    float* __restrict__ O1, int ld1, float* __restrict__ O2, int ld2)
{
    __shared__ ushort_t Bs[128 * 128];
    const int Mrows = nodes * PLANES;
    const int row0 = blockIdx.x * 128;
    const int cbase = blockIdx.y * 128;
    const int ctiles = min(8, (cols - cbase + 15) >> 4);
    const int tid = threadIdx.x;

    // ---- stage B panel (swizzled) ----
    {
        int cl = tid >> 1;
        int c = cbase + cl;
        int kh = (tid & 1) * 64;
        if (c < cols) {
            const uint4* src = (const uint4*)(Bt + (size_t)c * 128 + kh);
            #pragma unroll
            for (int i = 0; i < 8; ++i) {
                uint4 d = src[i];
                int off = cl * 256 + kh * 2 + i * 16;
                off ^= (cl & 7) << 4;
                *(uint4*)((char*)Bs + off) = d;
            }
        } else {
            #pragma unroll
            for (int i = 0; i < 8; ++i) {
                int off = cl * 256 + kh * 2 + i * 16;
                off ^= (cl & 7) << 4;
                *(uint4*)((char*)Bs + off) = make_uint4(0, 0, 0, 0);
            }
        }
    }
    __syncthreads();

    const int wv = tid >> 6;
    const int l = tid & 63;
    const int kg = l >> 4;          // k-group 0..3 (8 elems each)
    // A base pointers for 2 row-tiles
    const float* aptr[2];
    #pragma unroll
    for (int rt = 0; rt < 2; ++rt) {
        int rg = row0 + wv * 32 + rt * 16 + (l & 15);
        if (rg >= Mrows) rg = Mrows - 1;
        int node, pl;
        if (PLANES == 1) { node = rg; pl = 0; }
        else { node = rg / PLANES; pl = rg % PLANES; }
        const float* base = (pl == 0) ? A0 : (pl == 1) ? A1 : (pl == 2) ? A2 : A3;
        aptr[rt] = base + (size_t)node * 128 + kg * 8;
    }

    f32x4 acc[2][8];
    #pragma unroll
    for (int a = 0; a < 2; ++a)
        #pragma unroll
        for (int b = 0; b < 8; ++b)
            #pragma unroll
            for (int q = 0; q < 4; ++q) acc[a][b][q] = 0.f;

    #pragma unroll
    for (int kt = 0; kt < 4; ++kt) {
        short8 af[2];
        #pragma unroll
        for (int rt = 0; rt < 2; ++rt) {
            const float4* p = (const float4*)(aptr[rt] + kt * 32);
            float4 x0 = p[0];
            float4 x1 = p[1];
            union { uint_t u[4]; short8 s; } u;
            u.u[0] = cvt2(x0.x, x0.y);
            u.u[1] = cvt2(x0.z, x0.w);
            u.u[2] = cvt2(x1.x, x1.y);
            u.u[3] = cvt2(x1.z, x1.w);
            af[rt] = u.s;
        }
        for (int ct = 0; ct < ctiles; ++ct) {
            int off = ((ct * 16 + (l & 15)) * 256) + kt * 64 + (l >> 4) * 16;
            off ^= (l & 7) << 4;
            short8 bfr = *(const short8*)((const char*)Bs + off);
            acc[0][ct] = __builtin_amdgcn_mfma_f32_16x16x32_bf16(af[0], bfr, acc[0][ct], 0, 0, 0);
            acc[1][ct] = __builtin_amdgcn_mfma_f32_16x16x32_bf16(af[1], bfr, acc[1][ct], 0, 0, 0);
        }
    }

    // ---- epilogue: C layout col = l&15, row = (l>>4)*4 + j ----
    for (int ct = 0; ct < ctiles; ++ct) {
        int c = cbase + ct * 16 + (l & 15);
        if (c >= cols) continue;
        float bias_, slope_;
        float* optr;
        int ldo, co;
        if (c < colsplit) {
            bias_ = biasA ? biasA[c] : 0.f;
            slope_ = slopeA; optr = O1; ldo = ld1; co = c;
        } else {
            bias_ = biasB ? biasB[c - colsplit] : 0.f;
            slope_ = slopeB; optr = O2; ldo = ld2; co = c - colsplit;
        }
        #pragma unroll
        for (int rt = 0; rt < 2; ++rt) {
            #pragma unroll
            for (int j = 0; j < 4; ++j) {
                int rg = row0 + wv * 32 + rt * 16 + (l >> 4) * 4 + j;
                if (rg >= Mrows) continue;
                float v = acc[rt][ct][j] + bias_;
                v = v >= 0.f ? v : v * slope_;
                optr[(size_t)rg * ldo + co] = v;
            }
        }
    }
}

// ================= weight prep =================
// 2-matrix concat transpose: dst[col][k], col<128 from Wa, else Wb
__global__ __launch_bounds__(128) void prep2(
    const float* __restrict__ Wa, const float* __restrict__ Wb, ushort_t* __restrict__ dst)
{
    int c = blockIdx.x, k = threadIdx.x;
    const float* W = (c < 128) ? Wa : Wb;
    int cc = c & 127;
    dst[c * 128 + k] = f2bf(W[k * 128 + cc]);
}

// conv panel: cols 0-127 = W^T, 128-131 el folds, 132-135 er folds, 136-143 zero
__global__ __launch_bounds__(128) void prep_conv(
    const float* __restrict__ W, const float* __restrict__ al, const float* __restrict__ ar,
    ushort_t* __restrict__ dst)
{
    int c = blockIdx.x, k = threadIdx.x;
    float v = 0.f;
    if (c < 128) {
        v = W[k * 128 + c];
    } else if (c < 136) {
        int idx = c - 128;
        int g = idx & 3;
        const float* a = (idx < 4) ? al : ar;
        float s = 0.f;
        for (int d = 0; d < 32; ++d) s += W[k * 128 + g * 32 + d] * a[g * 32 + d];
        v = s;
    }
    dst[c * 128 + k] = f2bf(v);
}

// ================= batched CSR build =================
__global__ __launch_bounds__(256) void count_all(
    const int* __restrict__ dst0, const int* __restrict__ dst1, int* __restrict__ counts)
{
    int idx = blockIdx.x * 256 + threadIdx.x;
    if (idx < 3 * E0) {
        atomicAdd(&counts[(idx / E0) * N1 + dst0[idx]], 1);
    } else {
        int k = idx - 3 * E0;
        if (k < 3 * E1) atomicAdd(&counts[3 * N1 + (k / E1) * N2 + dst1[k]], 1);
    }
}

__global__ __launch_bounds__(1024) void scan_block_kernel(
    const int* __restrict__ counts, int* __restrict__ incl, int* __restrict__ bsum, int n)
{
    __shared__ int s[1024];
    int i = blockIdx.x * 1024 + threadIdx.x;
    int v = (i < n) ? counts[i] : 0;
    s[threadIdx.x] = v;
    __syncthreads();
    for (int off = 1; off < 1024; off <<= 1) {
        int t = (threadIdx.x >= off) ? s[threadIdx.x - off] : 0;
        __syncthreads();
        s[threadIdx.x] += t;
        __syncthreads();
    }
    if (i < n) incl[i] = s[threadIdx.x];
    if (threadIdx.x == 1023) bsum[blockIdx.x] = s[1023];
}

__global__ __launch_bounds__(256) void scan_bsum_block(int* bsum, int nb)
{
    __shared__ int s[256];
    int t = threadIdx.x;
    int v = (t < nb) ? bsum[t] : 0;
    s[t] = v;
    __syncthreads();
    for (int off = 1; off < 256; off <<= 1) {
        int tv = (t >= off) ? s[t - off] : 0;
        __syncthreads();
        s[t] += tv;
        __syncthreads();
    }
    if (t < nb) bsum[t] = s[t] - v;
    if (t == nb - 1) bsum[nb] = s[t];
}

__global__ __launch_bounds__(256) void scan_final_kernel(
    const int* __restrict__ counts, const int* __restrict__ incl,
    const int* __restrict__ bsum, int* __restrict__ offs, int* __restrict__ cursor,
    int n, int nb)
{
    int i = blockIdx.x * 256 + threadIdx.x;
    if (i < n) {
        int ex = incl[i] - counts[i] + bsum[i >> 10];
        offs[i] = ex;
        cursor[i] = ex;
    }
    if (i == 0) offs[n] = bsum[nb];
}

__global__ __launch_bounds__(256) void scatter_all(
    const int* __restrict__ dst0, const int* __restrict__ dst1,
    int* __restrict__ cursor, int* __restrict__ csr)
{
    int idx = blockIdx.x * 256 + threadIdx.x;
    if (idx < 3 * E0) {
        int rep = idx / E0, e = idx - rep * E0;
        int p = atomicAdd(&cursor[rep * N1 + dst0[idx]], 1);
        csr[p] = e;
    } else {
        int k = idx - 3 * E0;
        if (k < 3 * E1) {
            int rep = k / E1, e = k - rep * E1;
            int p = atomicAdd(&cursor[3 * N1 + rep * N2 + dst1[k]], 1);
            csr[p] = e;
        }
    }
}

// ================= softmax gather (single pass, P stride 144, elr embedded) ===
__global__ __launch_bounds__(256) void gat_gather3(
    const int* __restrict__ src, const int* __restrict__ csr,
    const int* __restrict__ offs, int nodeBase,
    const float* __restrict__ P, float* __restrict__ out)
{
    __shared__ float4 accs[8][32];
    __shared__ float reds[8][32];
    int node = blockIdx.x;
    int t = threadIdx.x;
    int lane = t & 31;
    int slot = t >> 5;
    int g = lane >> 3;
    int beg = offs[nodeBase + node], end = offs[nodeBase + node + 1];
    float erg = P[(size_t)node * 144 + 132 + g];
    float den = 0.f;
    float4 acc = make_float4(0.f, 0.f, 0.f, 0.f);
    for (int i = beg + slot; i < end; i += 8) {
        int e = csr[i];
        int s = src[e];
        float w = __expf(lrelu(P[(size_t)s * 144 + 128 + g] + erg, 0.2f));
        float4 p = ((const float4*)(P + (size_t)s * 144))[lane];
        den += w;
        acc.x += w * p.x; acc.y += w * p.y; acc.z += w * p.z; acc.w += w * p.w;
    }
    reds[slot][lane] = den;
    accs[slot][lane] = acc;
    __syncthreads();
    if (slot < 4) {
        reds[slot][lane] += reds[slot + 4][lane];
        float4 b = accs[slot + 4][lane];
        accs[slot][lane].x += b.x; accs[slot][lane].y += b.y;
        accs[slot][lane].z += b.z; accs[slot][lane].w += b.w;
    }
    __syncthreads();
    if (slot < 2) {
        reds[slot][lane] += reds[slot + 2][lane];
        float4 b = accs[slot + 2][lane];
        accs[slot][lane].x += b.x; accs[slot][lane].y += b.y;
        accs[slot][lane].z += b.z; accs[slot][lane].w += b.w;
    }
    __syncthreads();
    if (slot == 0) {
        float d = reds[0][lane] + reds[1][lane];
        float4 a0 = accs[0][lane], a1 = accs[1][lane];
        float inv = (end > beg) ? 1.f / d : 0.f;
        float4 o;
        o.x = lrelu((a0.x + a1.x) * inv, 0.01f);
        o.y = lrelu((a0.y + a1.y) * inv, 0.01f);
        o.z = lrelu((a0.z + a1.z) * inv, 0.01f);
        o.w = lrelu((a0.w + a1.w) * inv, 0.01f);
        ((float4*)(out + (size_t)node * 128))[lane] = o;
    }
}

// ================= gated attention combine (reads grv) =================
template <int K>
__global__ __launch_bounds__(256) void attn_combine2(
    const float* __restrict__ grv, const float* __restrict__ gl,
    const float* __restrict__ aW, int n, float* __restrict__ out1)
{
    int node = blockIdx.x * 2 + (threadIdx.x >> 7);
    int tid = threadIdx.x & 127;
    if (node >= n) return;
    float aw = aW[tid & 15];
    float glv = gl[(size_t)node * 128 + tid];
    float e[K];
    #pragma unroll
    for (int k = 0; k < K; ++k) {
        float z = lrelu(glv + grv[((size_t)node * K + k) * 256 + tid], 0.01f);
        float p = z * aw;
        p += __shfl_xor(p, 1);
        p += __shfl_xor(p, 2);
        p += __shfl_xor(p, 4);
        p += __shfl_xor(p, 8);
        e[k] = p;
    }
    float m = e[0];
    #pragma unroll
    for (int k = 1; k < K; ++k) m = fmaxf(m, e[k]);
    float s = 0.f, w[K];
    #pragma unroll
    for (int k = 0; k < K; ++k) { w[k] = __expf(e[k] - m); s += w[k]; }
    float inv = 1.f / s;
    float acc = 0.f;
    #pragma unroll
    for (int k = 0; k < K; ++k)
        acc += (w[k] * inv) * grv[((size_t)node * K + k) * 256 + 128 + tid];
    out1[(size_t)node * 128 + tid] = lrelu(acc, 0.01f);
}

// ================= final linear 128 -> 2 =================
__global__ __launch_bounds__(256) void lin_kernel(
    const float* __restrict__ H, const float* __restrict__ W,
    const float* __restrict__ b, float* __restrict__ out, int n)
{
    int idx = blockIdx.x * 256 + threadIdx.x;
    int node = idx >> 1, c = idx & 1;
    if (node >= n) return;
    float acc = 0.f;
    for (int k = 0; k < 128; ++k)
        acc += H[(size_t)node * 128 + k] * W[k * 2 + c];
    out[(size_t)node * 2 + c] = acc + b[c];
}

extern "C" void kernel_launch(void* const* d_in, const int* in_sizes, int n_in,
                              void* d_out, int out_size, void* d_ws, size_t ws_size,
                              hipStream_t stream)
{
    (void)in_sizes; (void)n_in; (void)out_size; (void)ws_size;
    const float* x       = (const float*)d_in[0];
    const int*   src0    = (const int*)d_in[1];
    const int*   dst0    = (const int*)d_in[2];
    const int*   src1    = (const int*)d_in[3];
    const int*   dst1    = (const int*)d_in[4];
    const float* conv_W  = (const float*)d_in[5];
    const float* conv_al = (const float*)d_in[6];
    const float* conv_ar = (const float*)d_in[7];
    const float* feat_W  = (const float*)d_in[8];
    const float* feat_b  = (const float*)d_in[9];
    const float* relWl_W = (const float*)d_in[10];
    const float* relWl_b = (const float*)d_in[11];
    const float* relWr_W = (const float*)d_in[12];
    const float* relWr_b = (const float*)d_in[13];
    const float* relP_W  = (const float*)d_in[14];
    const float* relP_b  = (const float*)d_in[15];
    const float* rela_W  = (const float*)d_in[16];
    const float* proj_W  = (const float*)d_in[18];
    const float* proj_b  = (const float*)d_in[19];
    const float* hopWl_W = (const float*)d_in[20];
    const float* hopWl_b = (const float*)d_in[21];
    const float* hopWr_W = (const float*)d_in[22];
    const float* hopWr_b = (const float*)d_in[23];
    const float* hopP_W  = (const float*)d_in[24];
    const float* hopP_b  = (const float*)d_in[25];
    const float* hopa_W  = (const float*)d_in[26];
    const float* lin_W   = (const float*)d_in[28];
    const float* lin_b   = (const float*)d_in[29];
    float* out = (float*)d_out;

    // ---- workspace layout (~222 MB, under proven 257 MB) ----
    char* base = (char*)d_ws;
    size_t off = 0;
    auto alloc = [&](size_t bytes) -> void* {
        void* p = base + off;
        off += (bytes + 255) & ~(size_t)255;
        return p;
    };
    char*  region1 = (char*)alloc((size_t)N0 * 144 * 4);   // 57.6 MB: P / grv / glhop
    float* F0      = (float*)alloc((size_t)N1 * 128 * 4);
    float* F1      = (float*)alloc((size_t)N1 * 128 * 4);
    float* F2      = (float*)alloc((size_t)N1 * 128 * 4);
    float* F3      = (float*)alloc((size_t)N1 * 128 * 4);
    float* glbuf   = (float*)alloc((size_t)N1 * 128 * 4);
    float* h1      = (float*)alloc((size_t)N1 * 128 * 4);
    int*   csr_all = (int*)alloc((size_t)NE_ALL * 4);
    int*   offs    = (int*)alloc((size_t)(N_TOT + 1) * 4);
    int*   bsum    = (int*)alloc(2048);
    ushort_t* pconv[6];
    for (int i = 0; i < 6; ++i) pconv[i] = (ushort_t*)alloc(144 * 128 * 2);
    ushort_t* p2L0 = (ushort_t*)alloc(256 * 128 * 2);
    ushort_t* p2L1 = (ushort_t*)alloc(256 * 128 * 2);
    ushort_t* pE   = (ushort_t*)alloc(256 * 128 * 2);
    ushort_t* pF0  = (ushort_t*)alloc(256 * 128 * 2);
    ushort_t* pF1  = (ushort_t*)alloc(256 * 128 * 2);
    ushort_t* pG   = (ushort_t*)alloc(256 * 128 * 2);

    float* P     = (float*)region1;
    float* grv   = (float*)region1;
    float* glhop = (float*)(region1 + 40000000);   // past hop grv (38.4 MB)
    float* h2    = F1;                              // aliases F1 after L1 attn GEMM reads
    float* hopp0 = F0;                              // proj plane, after L1 attn done
    float* hout  = glbuf;

    int* counts = (int*)glbuf;   // CSR temps alias glbuf (used before glbuf written)
    int* incl   = counts + N_TOT;
    int* cursor = incl + N_TOT;

    // ---- weight prep ----
    for (int i = 0; i < 6; ++i)
        prep_conv<<<144, 128, 0, stream>>>(conv_W + (size_t)i * 16384,
                                           conv_al + (size_t)i * 128,
                                           conv_ar + (size_t)i * 128, pconv[i]);
    prep2<<<256, 128, 0, stream>>>(feat_W, relWl_W, p2L0);
    prep2<<<256, 128, 0, stream>>>(feat_W + 16384, relWl_W + 16384, p2L1);
    prep2<<<256, 128, 0, stream>>>(proj_W, hopWl_W, pE);
    prep2<<<256, 128, 0, stream>>>(relWr_W, relP_W, pF0);
    prep2<<<256, 128, 0, stream>>>(relWr_W + 16384, relP_W + 16384, pF1);
    prep2<<<256, 128, 0, stream>>>(hopWr_W, hopP_W, pG);

    // ---- batched CSR ----
    hipMemsetAsync(counts, 0, (size_t)N_TOT * 4, stream);
    count_all<<<(NE_ALL + 255) / 256, 256, 0, stream>>>(dst0, dst1, counts);
    scan_block_kernel<<<NB_SCAN, 1024, 0, stream>>>(counts, incl, bsum, N_TOT);
    scan_bsum_block<<<1, 256, 0, stream>>>(bsum, NB_SCAN);
    scan_final_kernel<<<(N_TOT + 255) / 256, 256, 0, stream>>>(counts, incl, bsum, offs, cursor, N_TOT, NB_SCAN);
    scatter_all<<<(NE_ALL + 255) / 256, 256, 0, stream>>>(dst0, dst1, cursor, csr_all);

    const int CH = 12500;

    // ---- layer 0 ----
    for (int j = 0; j < 3; ++j) {
        gemm_bf16<1><<<dim3((N0 + 127) / 128, 2), 256, 0, stream>>>(
            x, x, x, x, N0, pconv[j], 136, nullptr, nullptr, 136, 1.f, 1.f,
            P, 144, nullptr, 0);
        float* Fj = (j == 0) ? F0 : (j == 1) ? F1 : F2;
        gat_gather3<<<N1, 256, 0, stream>>>(src0 + (size_t)j * E0, csr_all, offs, j * N1, P, Fj);
    }
    gemm_bf16<1><<<dim3((N1 + 127) / 128, 2), 256, 0, stream>>>(
        x, x, x, x, N1, p2L0, 256, feat_b, relWl_b, 128, 0.01f, 1.f,
        F3, 128, glbuf, 128);
    for (int c = 0; c < N1; c += CH) {
        gemm_bf16<4><<<dim3((CH * 4 + 127) / 128, 2), 256, 0, stream>>>(
            F0 + (size_t)c * 128, F1 + (size_t)c * 128, F2 + (size_t)c * 128, F3 + (size_t)c * 128,
            CH, pF0, 256, relWr_b, relP_b, 128, 1.f, 1.f,
            grv, 256, grv + 128, 256);
        attn_combine2<4><<<CH / 2, 256, 0, stream>>>(
            grv, glbuf + (size_t)c * 128, rela_W, CH, h1 + (size_t)c * 128);
    }

    // ---- layer 1 ----
    for (int j = 0; j < 3; ++j) {
        gemm_bf16<1><<<dim3((N1 + 127) / 128, 2), 256, 0, stream>>>(
            h1, h1, h1, h1, N1, pconv[3 + j], 136, nullptr, nullptr, 136, 1.f, 1.f,
            P, 144, nullptr, 0);
        float* Fj = (j == 0) ? F0 : (j == 1) ? F1 : F2;
        gat_gather3<<<N2, 256, 0, stream>>>(src1 + (size_t)j * E1, csr_all, offs, 3 * N1 + j * N2, P, Fj);
    }
    gemm_bf16<1><<<dim3((N2 + 127) / 128, 2), 256, 0, stream>>>(
        h1, h1, h1, h1, N2, p2L1, 256, feat_b + 128, relWl_b + 128, 128, 0.01f, 1.f,
        F3, 128, glbuf, 128);
    for (int c = 0; c < N2; c += CH) {
        gemm_bf16<4><<<dim3((CH * 4 + 127) / 128, 2), 256, 0, stream>>>(
            F0 + (size_t)c * 128, F1 + (size_t)c * 128, F2 + (size_t)c * 128, F3 + (size_t)c * 128,
            CH, pF1, 256, relWr_b + 128, relP_b + 128, 128, 1.f, 1.f,
            grv, 256, grv + 128, 256);
        attn_combine2<4><<<CH / 2, 256, 0, stream>>>(
            grv, glbuf + (size_t)c * 128, rela_W + 16, CH, h2 + (size_t)c * 128);
    }

    // ---- proj + hop gl (after F planes are dead) ----
    gemm_bf16<1><<<dim3((N2 + 127) / 128, 2), 256, 0, stream>>>(
        x, x, x, x, N2, pE, 256, proj_b, hopWl_b, 128, 1.f, 1.f,
        hopp0, 128, glhop, 128);

    // ---- hop attention over [proj, h1[:N2], h2] ----
    for (int c = 0; c < N2; c += CH) {
        gemm_bf16<3><<<dim3((CH * 3 + 127) / 128, 2), 256, 0, stream>>>(
            hopp0 + (size_t)c * 128, h1 + (size_t)c * 128, h2 + (size_t)c * 128, nullptr,
            CH, pG, 256, hopWr_b, hopP_b, 128, 1.f, 1.f,
            grv, 256, grv + 128, 256);
        attn_combine2<3><<<CH / 2, 256, 0, stream>>>(
            grv, glhop + (size_t)c * 128, hopa_W, CH, hout + (size_t)c * 128);
    }

    // ---- final linear ----
    lin_kernel<<<(N2 * 2 + 255) / 256, 256, 0, stream>>>(hout, lin_W, lin_b, out, N2);
}

// Round 6
// 1050.599 us; speedup vs baseline: 2.4321x; 2.4321x over previous
//
#include <hip/hip_runtime.h>

#define N0 100000
#define N1 50000
#define N2 25000
#define E0 500000
#define E1 250000
#define N_TOT (3 * N1 + 3 * N2)
#define NE_ALL (3 * E0 + 3 * E1)
#define NB_SCAN ((N_TOT + 1023) / 1024)

typedef __attribute__((ext_vector_type(8))) short short8;
typedef __attribute__((ext_vector_type(4))) float f32x4;
typedef unsigned short ushort_t;
typedef unsigned int uint_t;

static __device__ __forceinline__ float lrelu(float x, float s) {
    return x >= 0.f ? x : s * x;
}

static __device__ __forceinline__ ushort_t f2bf(float f) {
    union { float f; uint_t u; } v; v.f = f;
    uint_t r = v.u + 0x7FFFu + ((v.u >> 16) & 1u);
    return (ushort_t)(r >> 16);
}

static __device__ __forceinline__ float bf2f(ushort_t u) {
    union { uint_t i; float f; } v; v.i = ((uint_t)u) << 16;
    return v.f;
}

static __device__ __forceinline__ uint_t cvt2(float lo, float hi) {
    uint_t r;
    asm("v_cvt_pk_bf16_f32 %0, %1, %2" : "=v"(r) : "v"(lo), "v"(hi));
    return r;
}

// ================= MFMA GEMM =================
// 256 thr = 4 waves; tile 128 rows x CT*16 cols. A: f32 global (PLANES
// row-interleaved planes), cvt to bf16 in-reg. B: bf16 [col][k] panel staged
// to LDS (XOR swizzle). Epilogue: bias+lrelu in-reg -> LDS transpose ->
// full-row float4 / packed-bf16 stores.
// OUTMODE 0: f32 outputs, GLOBAL col < colsplit -> O1 else O2.
// OUTMODE 1 (conv): col<128 -> bf16 O1 (P), col>=128 -> f32 O2 (elr, ld2=8).
template <int CT, int PLANES, int OUTMODE>
__global__ __launch_bounds__(256) void gemm_bf16(
    const float* __restrict__ A0, const float* __restrict__ A1,
    const float* __restrict__ A2, const float* __restrict__ A3,
    int nodes, const ushort_t* __restrict__ Bt, int cols,
    const float* __restrict__ biasA, const float* __restrict__ biasB,
    int colsplit, float slopeA, float slopeB,
    void* __restrict__ O1, int ld1, float* __restrict__ O2, int ld2)
{
    constexpr int BCOLS = CT * 16;
    constexpr int CSTR = BCOLS + 4;
    constexpr int SH_B = BCOLS * 256;
    constexpr int SH_C = 64 * CSTR * 4;
    constexpr int SHSZ = SH_B > SH_C ? SH_B : SH_C;
    __shared__ char sh[SHSZ];
    float* Cs = (float*)sh;

    const int Mrows = nodes * PLANES;
    const int row0 = blockIdx.x * 128;
    const int cbase = blockIdx.y * BCOLS;
    const int tid = threadIdx.x;

    // ---- stage B panel (swizzled) ----
    for (int cl = tid >> 1; cl < BCOLS; cl += 128) {
        int c = cbase + cl;
        int kh = (tid & 1) * 64;
        if (c < cols) {
            const uint4* srcp = (const uint4*)(Bt + (size_t)c * 128 + kh);
            #pragma unroll
            for (int i = 0; i < 8; ++i) {
                uint4 d = srcp[i];
                int off = cl * 256 + kh * 2 + i * 16;
                off ^= (cl & 7) << 4;
                *(uint4*)(sh + off) = d;
            }
        } else {
            #pragma unroll
            for (int i = 0; i < 8; ++i) {
                int off = cl * 256 + kh * 2 + i * 16;
                off ^= (cl & 7) << 4;
                *(uint4*)(sh + off) = make_uint4(0, 0, 0, 0);
            }
        }
    }
    __syncthreads();

    const int wv = tid >> 6;
    const int l = tid & 63;
    const int kg = l >> 4;
    const float* aptr[2];
    #pragma unroll
    for (int rt = 0; rt < 2; ++rt) {
        int rg = row0 + wv * 32 + rt * 16 + (l & 15);
        if (rg >= Mrows) rg = Mrows - 1;
        int node, pl;
        if (PLANES == 1) { node = rg; pl = 0; }
        else { node = rg / PLANES; pl = rg % PLANES; }
        const float* base = (pl == 0) ? A0 : (pl == 1) ? A1 : (pl == 2) ? A2 : A3;
        aptr[rt] = base + (size_t)node * 128 + kg * 8;
    }

    f32x4 acc[2][CT];
    #pragma unroll
    for (int a = 0; a < 2; ++a)
        #pragma unroll
        for (int b = 0; b < CT; ++b)
            #pragma unroll
            for (int q = 0; q < 4; ++q) acc[a][b][q] = 0.f;

    #pragma unroll
    for (int kt = 0; kt < 4; ++kt) {
        short8 af[2];
        #pragma unroll
        for (int rt = 0; rt < 2; ++rt) {
            const float4* p = (const float4*)(aptr[rt] + kt * 32);
            float4 x0 = p[0];
            float4 x1 = p[1];
            union { uint_t u[4]; short8 s; } u;
            u.u[0] = cvt2(x0.x, x0.y);
            u.u[1] = cvt2(x0.z, x0.w);
            u.u[2] = cvt2(x1.x, x1.y);
            u.u[3] = cvt2(x1.z, x1.w);
            af[rt] = u.s;
        }
        #pragma unroll
        for (int ct = 0; ct < CT; ++ct) {
            int off = ((ct * 16 + (l & 15)) * 256) + kt * 64 + (l >> 4) * 16;
            off ^= (l & 7) << 4;
            short8 bfr = *(const short8*)(sh + off);
            acc[0][ct] = __builtin_amdgcn_mfma_f32_16x16x32_bf16(af[0], bfr, acc[0][ct], 0, 0, 0);
            acc[1][ct] = __builtin_amdgcn_mfma_f32_16x16x32_bf16(af[1], bfr, acc[1][ct], 0, 0, 0);
        }
    }

    // ---- epilogue: LDS transpose, then clean vector stores ----
    #pragma unroll
    for (int rt = 0; rt < 2; ++rt) {
        __syncthreads();   // B reads / previous store pass done
        #pragma unroll
        for (int ct = 0; ct < CT; ++ct) {
            int c = cbase + ct * 16 + (l & 15);
            float bias_ = 0.f, slope_ = 1.f;
            if (c < colsplit) {
                if (biasA) bias_ = biasA[c];
                slope_ = slopeA;
            } else if (c < cols) {
                if (biasB) bias_ = biasB[c - colsplit];
                slope_ = slopeB;
            }
            int lrow = wv * 16 + (l >> 4) * 4;
            #pragma unroll
            for (int j = 0; j < 4; ++j) {
                float v = acc[rt][ct][j] + bias_;
                v = v >= 0.f ? v : v * slope_;
                Cs[(lrow + j) * CSTR + ct * 16 + (l & 15)] = v;
            }
        }
        __syncthreads();
        for (int i = tid; i < 64 * CT * 4; i += 256) {
            int rho = i / (CT * 4);
            int c4 = i - rho * (CT * 4);
            int col = c4 * 4;            // LOCAL col within panel
            int gcol = cbase + col;      // GLOBAL col (routing/offset!)
            int rg = row0 + rt * 16 + (rho >> 4) * 32 + (rho & 15);
            if (rg >= Mrows || gcol >= cols) continue;
            float4 v = *(const float4*)&Cs[rho * CSTR + col];
            if (OUTMODE == 1) {
                if (gcol < 128) {
                    uint2 pk;
                    pk.x = cvt2(v.x, v.y);
                    pk.y = cvt2(v.z, v.w);
                    *(uint2*)((ushort_t*)O1 + (size_t)rg * ld1 + gcol) = pk;
                } else {
                    *(float4*)(O2 + (size_t)rg * ld2 + (gcol - 128)) = v;
                }
            } else {
                if (gcol < colsplit)
                    *(float4*)((float*)O1 + (size_t)rg * ld1 + gcol) = v;
                else
                    *(float4*)(O2 + (size_t)rg * ld2 + (gcol - colsplit)) = v;
            }
        }
    }
}

// ================= weight prep =================
__global__ __launch_bounds__(128) void prep2(
    const float* __restrict__ Wa, const float* __restrict__ Wb, ushort_t* __restrict__ dst)
{
    int c = blockIdx.x, k = threadIdx.x;
    const float* W = (c < 128) ? Wa : Wb;
    int cc = c & 127;
    dst[c * 128 + k] = f2bf(W[k * 128 + cc]);
}

// conv panel: cols 0-127 = W^T, 128-131 el folds (W@al), 132-135 er folds
__global__ __launch_bounds__(128) void prep_conv(
    const float* __restrict__ W, const float* __restrict__ al, const float* __restrict__ ar,
    ushort_t* __restrict__ dst)
{
    int c = blockIdx.x, k = threadIdx.x;
    float v;
    if (c < 128) {
        v = W[k * 128 + c];
    } else {
        int idx = c - 128;
        int g = idx & 3;
        const float* a = (idx < 4) ? al : ar;
        float s = 0.f;
        for (int d = 0; d < 32; ++d) s += W[k * 128 + g * 32 + d] * a[g * 32 + d];
        v = s;
    }
    dst[c * 128 + k] = f2bf(v);
}

// ================= batched CSR build =================
__global__ __launch_bounds__(256) void count_all(
    const int* __restrict__ dst0, const int* __restrict__ dst1, int* __restrict__ counts)
{
    int idx = blockIdx.x * 256 + threadIdx.x;
    if (idx < 3 * E0) {
        atomicAdd(&counts[(idx / E0) * N1 + dst0[idx]], 1);
    } else {
        int k = idx - 3 * E0;
        if (k < 3 * E1) atomicAdd(&counts[3 * N1 + (k / E1) * N2 + dst1[k]], 1);
    }
}

__global__ __launch_bounds__(1024) void scan_block_kernel(
    const int* __restrict__ counts, int* __restrict__ incl, int* __restrict__ bsum, int n)
{
    __shared__ int s[1024];
    int i = blockIdx.x * 1024 + threadIdx.x;
    int v = (i < n) ? counts[i] : 0;
    s[threadIdx.x] = v;
    __syncthreads();
    for (int off = 1; off < 1024; off <<= 1) {
        int t = (threadIdx.x >= off) ? s[threadIdx.x - off] : 0;
        __syncthreads();
        s[threadIdx.x] += t;
        __syncthreads();
    }
    if (i < n) incl[i] = s[threadIdx.x];
    if (threadIdx.x == 1023) bsum[blockIdx.x] = s[1023];
}

__global__ __launch_bounds__(256) void scan_bsum_block(int* bsum, int nb)
{
    __shared__ int s[256];
    int t = threadIdx.x;
    int v = (t < nb) ? bsum[t] : 0;
    s[t] = v;
    __syncthreads();
    for (int off = 1; off < 256; off <<= 1) {
        int tv = (t >= off) ? s[t - off] : 0;
        __syncthreads();
        s[t] += tv;
        __syncthreads();
    }
    if (t < nb) bsum[t] = s[t] - v;
    if (t == nb - 1) bsum[nb] = s[t];
}

__global__ __launch_bounds__(256) void scan_final_kernel(
    const int* __restrict__ counts, const int* __restrict__ incl,
    const int* __restrict__ bsum, int* __restrict__ offs, int* __restrict__ cursor,
    int n, int nb)
{
    int i = blockIdx.x * 256 + threadIdx.x;
    if (i < n) {
        int ex = incl[i] - counts[i] + bsum[i >> 10];
        offs[i] = ex;
        cursor[i] = ex;
    }
    if (i == 0) offs[n] = bsum[nb];
}

// stores SRC NODE ID directly
__global__ __launch_bounds__(256) void scatter_all(
    const int* __restrict__ src0, const int* __restrict__ dst0,
    const int* __restrict__ src1, const int* __restrict__ dst1,
    int* __restrict__ cursor, int* __restrict__ csr)
{
    int idx = blockIdx.x * 256 + threadIdx.x;
    if (idx < 3 * E0) {
        int p = atomicAdd(&cursor[(idx / E0) * N1 + dst0[idx]], 1);
        csr[p] = src0[idx];
    } else {
        int k = idx - 3 * E0;
        if (k < 3 * E1) {
            int p = atomicAdd(&cursor[3 * N1 + (k / E1) * N2 + dst1[k]], 1);
            csr[p] = src1[k];
        }
    }
}

// ================= softmax gather (bf16 P, elr f32 [n][8]) =================
__global__ __launch_bounds__(256) void gat_gather3(
    const int* __restrict__ csrc, const int* __restrict__ offs, int nodeBase,
    const float* __restrict__ elr, const ushort_t* __restrict__ P,
    float* __restrict__ out)
{
    __shared__ float4 accs[8][32];
    __shared__ float reds[8][32];
    int node = blockIdx.x;
    int t = threadIdx.x;
    int lane = t & 31;
    int slot = t >> 5;
    int g = lane >> 3;
    int beg = offs[nodeBase + node], end = offs[nodeBase + node + 1];
    float erg = elr[(size_t)node * 8 + 4 + g];
    float den = 0.f;
    float4 acc = make_float4(0.f, 0.f, 0.f, 0.f);
    for (int i = beg + slot; i < end; i += 8) {
        int s = csrc[i];
        float w = __expf(lrelu(elr[(size_t)s * 8 + g] + erg, 0.2f));
        ushort4 p = *(const ushort4*)(P + (size_t)s * 128 + lane * 4);
        den += w;
        acc.x += w * bf2f(p.x); acc.y += w * bf2f(p.y);
        acc.z += w * bf2f(p.z); acc.w += w * bf2f(p.w);
    }
    reds[slot][lane] = den;
    accs[slot][lane] = acc;
    __syncthreads();
    if (slot < 4) {
        reds[slot][lane] += reds[slot + 4][lane];
        float4 b = accs[slot + 4][lane];
        accs[slot][lane].x += b.x; accs[slot][lane].y += b.y;
        accs[slot][lane].z += b.z; accs[slot][lane].w += b.w;
    }
    __syncthreads();
    if (slot < 2) {
        reds[slot][lane] += reds[slot + 2][lane];
        float4 b = accs[slot + 2][lane];
        accs[slot][lane].x += b.x; accs[slot][lane].y += b.y;
        accs[slot][lane].z += b.z; accs[slot][lane].w += b.w;
    }
    __syncthreads();
    if (slot == 0) {
        float d = reds[0][lane] + reds[1][lane];
        float4 a0 = accs[0][lane], a1 = accs[1][lane];
        float inv = (end > beg) ? 1.f / d : 0.f;
        float4 o;
        o.x = lrelu((a0.x + a1.x) * inv, 0.01f);
        o.y = lrelu((a0.y + a1.y) * inv, 0.01f);
        o.z = lrelu((a0.z + a1.z) * inv, 0.01f);
        o.w = lrelu((a0.w + a1.w) * inv, 0.01f);
        ((float4*)(out + (size_t)node * 128))[lane] = o;
    }
}

// ================= gated attention combine =================
template <int K>
__global__ __launch_bounds__(256) void attn_combine2(
    const float* __restrict__ grv, const float* __restrict__ gl,
    const float* __restrict__ aW, int n, float* __restrict__ out1)
{
    int node = blockIdx.x * 2 + (threadIdx.x >> 7);
    int tid = threadIdx.x & 127;
    if (node >= n) return;
    float aw = aW[tid & 15];
    float glv = gl[(size_t)node * 128 + tid];
    float e[K];
    #pragma unroll
    for (int k = 0; k < K; ++k) {
        float z = lrelu(glv + grv[((size_t)node * K + k) * 256 + tid], 0.01f);
        float p = z * aw;
        p += __shfl_xor(p, 1);
        p += __shfl_xor(p, 2);
        p += __shfl_xor(p, 4);
        p += __shfl_xor(p, 8);
        e[k] = p;
    }
    float m = e[0];
    #pragma unroll
    for (int k = 1; k < K; ++k) m = fmaxf(m, e[k]);
    float s = 0.f, w[K];
    #pragma unroll
    for (int k = 0; k < K; ++k) { w[k] = __expf(e[k] - m); s += w[k]; }
    float inv = 1.f / s;
    float acc = 0.f;
    #pragma unroll
    for (int k = 0; k < K; ++k)
        acc += (w[k] * inv) * grv[((size_t)node * K + k) * 256 + 128 + tid];
    out1[(size_t)node * 128 + tid] = lrelu(acc, 0.01f);
}

// ================= final linear 128 -> 2 =================
__global__ __launch_bounds__(256) void lin_kernel(
    const float* __restrict__ H, const float* __restrict__ W,
    const float* __restrict__ b, float* __restrict__ out, int n)
{
    int idx = blockIdx.x * 256 + threadIdx.x;
    int node = idx >> 1, c = idx & 1;
    if (node >= n) return;
    float acc = 0.f;
    for (int k = 0; k < 128; ++k)
        acc += H[(size_t)node * 128 + k] * W[k * 2 + c];
    out[(size_t)node * 2 + c] = acc + b[c];
}

extern "C" void kernel_launch(void* const* d_in, const int* in_sizes, int n_in,
                              void* d_out, int out_size, void* d_ws, size_t ws_size,
                              hipStream_t stream)
{
    (void)in_sizes; (void)n_in; (void)out_size; (void)ws_size;
    const float* x       = (const float*)d_in[0];
    const int*   src0    = (const int*)d_in[1];
    const int*   dst0    = (const int*)d_in[2];
    const int*   src1    = (const int*)d_in[3];
    const int*   dst1    = (const int*)d_in[4];
    const float* conv_W  = (const float*)d_in[5];
    const float* conv_al = (const float*)d_in[6];
    const float* conv_ar = (const float*)d_in[7];
    const float* feat_W  = (const float*)d_in[8];
    const float* feat_b  = (const float*)d_in[9];
    const float* relWl_W = (const float*)d_in[10];
    const float* relWl_b = (const float*)d_in[11];
    const float* relWr_W = (const float*)d_in[12];
    const float* relWr_b = (const float*)d_in[13];
    const float* relP_W  = (const float*)d_in[14];
    const float* relP_b  = (const float*)d_in[15];
    const float* rela_W  = (const float*)d_in[16];
    const float* proj_W  = (const float*)d_in[18];
    const float* proj_b  = (const float*)d_in[19];
    const float* hopWl_W = (const float*)d_in[20];
    const float* hopWl_b = (const float*)d_in[21];
    const float* hopWr_W = (const float*)d_in[22];
    const float* hopWr_b = (const float*)d_in[23];
    const float* hopP_W  = (const float*)d_in[24];
    const float* hopP_b  = (const float*)d_in[25];
    const float* hopa_W  = (const float*)d_in[26];
    const float* lin_W   = (const float*)d_in[28];
    const float* lin_b   = (const float*)d_in[29];
    float* out = (float*)d_out;

    // ---- workspace layout (~244 MB) ----
    char* base = (char*)d_ws;
    size_t off = 0;
    auto alloc = [&](size_t bytes) -> void* {
        void* p = base + off;
        off += (bytes + 255) & ~(size_t)255;
        return p;
    };
    ushort_t* P     = (ushort_t*)alloc((size_t)N0 * 128 * 2);   // bf16 conv proj
    float* elr      = (float*)alloc((size_t)N0 * 8 * 4);        // el[0:4], er[4:8]
    float* F0       = (float*)alloc((size_t)N1 * 128 * 4);
    float* F1       = (float*)alloc((size_t)N1 * 128 * 4);
    float* F2       = (float*)alloc((size_t)N1 * 128 * 4);
    float* F3       = (float*)alloc((size_t)N1 * 128 * 4);
    float* glbuf    = (float*)alloc((size_t)N1 * 128 * 4);
    float* h1       = (float*)alloc((size_t)N1 * 128 * 4);
    float* grv      = (float*)alloc((size_t)N1 * 256 * 4);      // 51.2 MB
    int*   csr_all  = (int*)alloc((size_t)NE_ALL * 4);
    int*   offs     = (int*)alloc((size_t)(N_TOT + 1) * 4);
    int*   bsum     = (int*)alloc(2048);
    ushort_t* pconv[6];
    for (int i = 0; i < 6; ++i) pconv[i] = (ushort_t*)alloc(136 * 128 * 2);
    ushort_t* p2L0 = (ushort_t*)alloc(256 * 128 * 2);
    ushort_t* p2L1 = (ushort_t*)alloc(256 * 128 * 2);
    ushort_t* pE   = (ushort_t*)alloc(256 * 128 * 2);
    ushort_t* pF0  = (ushort_t*)alloc(256 * 128 * 2);
    ushort_t* pF1  = (ushort_t*)alloc(256 * 128 * 2);
    ushort_t* pG   = (ushort_t*)alloc(256 * 128 * 2);

    float* glhop = (float*)((char*)grv + 38400000);  // hop grv uses 38.4 MB
    float* h2    = F1;
    float* hopp0 = F0;
    float* hout  = glbuf;

    int* counts = (int*)glbuf;  // CSR temps: used strictly before glbuf written
    int* incl   = counts + N_TOT;
    int* cursor = incl + N_TOT;

    // ---- weight prep ----
    for (int i = 0; i < 6; ++i)
        prep_conv<<<136, 128, 0, stream>>>(conv_W + (size_t)i * 16384,
                                           conv_al + (size_t)i * 128,
                                           conv_ar + (size_t)i * 128, pconv[i]);
    prep2<<<256, 128, 0, stream>>>(feat_W, relWl_W, p2L0);
    prep2<<<256, 128, 0, stream>>>(feat_W + 16384, relWl_W + 16384, p2L1);
    prep2<<<256, 128, 0, stream>>>(proj_W, hopWl_W, pE);
    prep2<<<256, 128, 0, stream>>>(relWr_W, relP_W, pF0);
    prep2<<<256, 128, 0, stream>>>(relWr_W + 16384, relP_W + 16384, pF1);
    prep2<<<256, 128, 0, stream>>>(hopWr_W, hopP_W, pG);

    // ---- batched CSR ----
    hipMemsetAsync(counts, 0, (size_t)N_TOT * 4, stream);
    count_all<<<(NE_ALL + 255) / 256, 256, 0, stream>>>(dst0, dst1, counts);
    scan_block_kernel<<<NB_SCAN, 1024, 0, stream>>>(counts, incl, bsum, N_TOT);
    scan_bsum_block<<<1, 256, 0, stream>>>(bsum, NB_SCAN);
    scan_final_kernel<<<(N_TOT + 255) / 256, 256, 0, stream>>>(counts, incl, bsum, offs, cursor, N_TOT, NB_SCAN);
    scatter_all<<<(NE_ALL + 255) / 256, 256, 0, stream>>>(src0, dst0, src1, dst1, cursor, csr_all);

    const int CH = 12500;

    // ---- layer 0 ----
    for (int j = 0; j < 3; ++j) {
        gemm_bf16<9, 1, 1><<<dim3((N0 + 127) / 128, 1), 256, 0, stream>>>(
            x, x, x, x, N0, pconv[j], 136, nullptr, nullptr, 128, 1.f, 1.f,
            P, 128, elr, 8);
        float* Fj = (j == 0) ? F0 : (j == 1) ? F1 : F2;
        gat_gather3<<<N1, 256, 0, stream>>>(csr_all, offs, j * N1, elr, P, Fj);
    }
    gemm_bf16<8, 1, 0><<<dim3((N1 + 127) / 128, 2), 256, 0, stream>>>(
        x, x, x, x, N1, p2L0, 256, feat_b, relWl_b, 128, 0.01f, 1.f,
        F3, 128, glbuf, 128);
    for (int c = 0; c < N1; c += CH) {
        gemm_bf16<8, 4, 0><<<dim3((CH * 4 + 127) / 128, 2), 256, 0, stream>>>(
            F0 + (size_t)c * 128, F1 + (size_t)c * 128, F2 + (size_t)c * 128, F3 + (size_t)c * 128,
            CH, pF0, 256, relWr_b, relP_b, 128, 1.f, 1.f,
            grv, 256, grv + 128, 256);
        attn_combine2<4><<<CH / 2, 256, 0, stream>>>(
            grv, glbuf + (size_t)c * 128, rela_W, CH, h1 + (size_t)c * 128);
    }

    // ---- layer 1 ----
    for (int j = 0; j < 3; ++j) {
        gemm_bf16<9, 1, 1><<<dim3((N1 + 127) / 128, 1), 256, 0, stream>>>(
            h1, h1, h1, h1, N1, pconv[3 + j], 136, nullptr, nullptr, 128, 1.f, 1.f,
            P, 128, elr, 8);
        float* Fj = (j == 0) ? F0 : (j == 1) ? F1 : F2;
        gat_gather3<<<N2, 256, 0, stream>>>(csr_all, offs, 3 * N1 + j * N2, elr, P, Fj);
    }
    gemm_bf16<8, 1, 0><<<dim3((N2 + 127) / 128, 2), 256, 0, stream>>>(
        h1, h1, h1, h1, N2, p2L1, 256, feat_b + 128, relWl_b + 128, 128, 0.01f, 1.f,
        F3, 128, glbuf, 128);
    for (int c = 0; c < N2; c += CH) {
        gemm_bf16<8, 4, 0><<<dim3((CH * 4 + 127) / 128, 2), 256, 0, stream>>>(
            F0 + (size_t)c * 128, F1 + (size_t)c * 128, F2 + (size_t)c * 128, F3 + (size_t)c * 128,
            CH, pF1, 256, relWr_b + 128, relP_b + 128, 128, 1.f, 1.f,
            grv, 256, grv + 128, 256);
        attn_combine2<4><<<CH / 2, 256, 0, stream>>>(
            grv, glbuf + (size_t)c * 128, rela_W + 16, CH, h2 + (size_t)c * 128);
    }

    // ---- proj + hop gl ----
    gemm_bf16<8, 1, 0><<<dim3((N2 + 127) / 128, 2), 256, 0, stream>>>(
        x, x, x, x, N2, pE, 256, proj_b, hopWl_b, 128, 1.f, 1.f,
        hopp0, 128, glhop, 128);

    // ---- hop attention over [proj, h1[:N2], h2] ----
    for (int c = 0; c < N2; c += CH) {
        gemm_bf16<8, 3, 0><<<dim3((CH * 3 + 127) / 128, 2), 256, 0, stream>>>(
            hopp0 + (size_t)c * 128, h1 + (size_t)c * 128, h2 + (size_t)c * 128, hopp0,
            CH, pG, 256, hopWr_b, hopP_b, 128, 1.f, 1.f,
            grv, 256, grv + 128, 256);
        attn_combine2<3><<<CH / 2, 256, 0, stream>>>(
            grv, glhop + (size_t)c * 128, hopa_W, CH, hout + (size_t)c * 128);
    }

    // ---- final linear ----
    lin_kernel<<<(N2 * 2 + 255) / 256, 256, 0, stream>>>(hout, lin_W, lin_b, out, N2);
}

// Round 7
// 836.362 us; speedup vs baseline: 3.0551x; 1.2562x over previous
//
#include <hip/hip_runtime.h>

#define N0 100000
#define N1 50000
#define N2 25000
#define E0 500000
#define E1 250000
#define N_TOT (3 * N1 + 3 * N2)
#define NE_ALL (3 * E0 + 3 * E1)
#define BNODE 512
#define NBUCK ((N_TOT + BNODE - 1) / BNODE)   // 440
#define BCAP 12288

typedef __attribute__((ext_vector_type(8))) short short8;
typedef __attribute__((ext_vector_type(4))) float f32x4;
typedef unsigned short ushort_t;
typedef unsigned int uint_t;

static __device__ __forceinline__ float lrelu(float x, float s) {
    return x >= 0.f ? x : s * x;
}

static __device__ __forceinline__ ushort_t f2bf(float f) {
    union { float f; uint_t u; } v; v.f = f;
    uint_t r = v.u + 0x7FFFu + ((v.u >> 16) & 1u);
    return (ushort_t)(r >> 16);
}

static __device__ __forceinline__ float bf2f(ushort_t u) {
    union { uint_t i; float f; } v; v.i = ((uint_t)u) << 16;
    return v.f;
}

static __device__ __forceinline__ uint_t cvt2(float lo, float hi) {
    uint_t r;
    asm("v_cvt_pk_bf16_f32 %0, %1, %2" : "=v"(r) : "v"(lo), "v"(hi));
    return r;
}

// ================= MFMA GEMM =================
// 256 thr = 4 waves; tile 128 rows x CT*16 cols. A: f32 global (PLANES
// row-interleaved planes), cvt to bf16 in-reg. B: bf16 [col][k] panel staged
// to LDS (XOR swizzle). Epilogue: bias+lrelu in-reg -> LDS transpose ->
// full-row float4 / packed-bf16 stores.
// OUTMODE 0: f32 outputs, GLOBAL col < colsplit -> O1 else O2.
// OUTMODE 1 (conv): col<128 -> bf16 O1 (P), col>=128 -> f32 O2 (elr, ld2=8).
template <int CT, int PLANES, int OUTMODE>
__global__ __launch_bounds__(256) void gemm_bf16(
    const float* __restrict__ A0, const float* __restrict__ A1,
    const float* __restrict__ A2, const float* __restrict__ A3,
    int nodes, const ushort_t* __restrict__ Bt, int cols,
    const float* __restrict__ biasA, const float* __restrict__ biasB,
    int colsplit, float slopeA, float slopeB,
    void* __restrict__ O1, int ld1, float* __restrict__ O2, int ld2)
{
    constexpr int BCOLS = CT * 16;
    constexpr int CSTR = BCOLS + 4;
    constexpr int SH_B = BCOLS * 256;
    constexpr int SH_C = 64 * CSTR * 4;
    constexpr int SHSZ = SH_B > SH_C ? SH_B : SH_C;
    __shared__ char sh[SHSZ];
    float* Cs = (float*)sh;

    const int Mrows = nodes * PLANES;
    const int row0 = blockIdx.x * 128;
    const int cbase = blockIdx.y * BCOLS;
    const int tid = threadIdx.x;

    // ---- stage B panel (swizzled) ----
    for (int cl = tid >> 1; cl < BCOLS; cl += 128) {
        int c = cbase + cl;
        int kh = (tid & 1) * 64;
        if (c < cols) {
            const uint4* srcp = (const uint4*)(Bt + (size_t)c * 128 + kh);
            #pragma unroll
            for (int i = 0; i < 8; ++i) {
                uint4 d = srcp[i];
                int off = cl * 256 + kh * 2 + i * 16;
                off ^= (cl & 7) << 4;
                *(uint4*)(sh + off) = d;
            }
        } else {
            #pragma unroll
            for (int i = 0; i < 8; ++i) {
                int off = cl * 256 + kh * 2 + i * 16;
                off ^= (cl & 7) << 4;
                *(uint4*)(sh + off) = make_uint4(0, 0, 0, 0);
            }
        }
    }
    __syncthreads();

    const int wv = tid >> 6;
    const int l = tid & 63;
    const int kg = l >> 4;
    const float* aptr[2];
    #pragma unroll
    for (int rt = 0; rt < 2; ++rt) {
        int rg = row0 + wv * 32 + rt * 16 + (l & 15);
        if (rg >= Mrows) rg = Mrows - 1;
        int node, pl;
        if (PLANES == 1) { node = rg; pl = 0; }
        else { node = rg / PLANES; pl = rg % PLANES; }
        const float* base = (pl == 0) ? A0 : (pl == 1) ? A1 : (pl == 2) ? A2 : A3;
        aptr[rt] = base + (size_t)node * 128 + kg * 8;
    }

    f32x4 acc[2][CT];
    #pragma unroll
    for (int a = 0; a < 2; ++a)
        #pragma unroll
        for (int b = 0; b < CT; ++b)
            #pragma unroll
            for (int q = 0; q < 4; ++q) acc[a][b][q] = 0.f;

    #pragma unroll
    for (int kt = 0; kt < 4; ++kt) {
        short8 af[2];
        #pragma unroll
        for (int rt = 0; rt < 2; ++rt) {
            const float4* p = (const float4*)(aptr[rt] + kt * 32);
            float4 x0 = p[0];
            float4 x1 = p[1];
            union { uint_t u[4]; short8 s; } u;
            u.u[0] = cvt2(x0.x, x0.y);
            u.u[1] = cvt2(x0.z, x0.w);
            u.u[2] = cvt2(x1.x, x1.y);
            u.u[3] = cvt2(x1.z, x1.w);
            af[rt] = u.s;
        }
        #pragma unroll
        for (int ct = 0; ct < CT; ++ct) {
            int off = ((ct * 16 + (l & 15)) * 256) + kt * 64 + (l >> 4) * 16;
            off ^= (l & 7) << 4;
            short8 bfr = *(const short8*)(sh + off);
            acc[0][ct] = __builtin_amdgcn_mfma_f32_16x16x32_bf16(af[0], bfr, acc[0][ct], 0, 0, 0);
            acc[1][ct] = __builtin_amdgcn_mfma_f32_16x16x32_bf16(af[1], bfr, acc[1][ct], 0, 0, 0);
        }
    }

    // ---- epilogue: LDS transpose, then clean vector stores ----
    #pragma unroll
    for (int rt = 0; rt < 2; ++rt) {
        __syncthreads();
        #pragma unroll
        for (int ct = 0; ct < CT; ++ct) {
            int c = cbase + ct * 16 + (l & 15);
            float bias_ = 0.f, slope_ = 1.f;
            if (c < colsplit) {
                if (biasA) bias_ = biasA[c];
                slope_ = slopeA;
            } else if (c < cols) {
                if (biasB) bias_ = biasB[c - colsplit];
                slope_ = slopeB;
            }
            int lrow = wv * 16 + (l >> 4) * 4;
            #pragma unroll
            for (int j = 0; j < 4; ++j) {
                float v = acc[rt][ct][j] + bias_;
                v = v >= 0.f ? v : v * slope_;
                Cs[(lrow + j) * CSTR + ct * 16 + (l & 15)] = v;
            }
        }
        __syncthreads();
        for (int i = tid; i < 64 * CT * 4; i += 256) {
            int rho = i / (CT * 4);
            int c4 = i - rho * (CT * 4);
            int col = c4 * 4;            // LOCAL col within panel
            int gcol = cbase + col;      // GLOBAL col
            int rg = row0 + rt * 16 + (rho >> 4) * 32 + (rho & 15);
            if (rg >= Mrows || gcol >= cols) continue;
            float4 v = *(const float4*)&Cs[rho * CSTR + col];
            if (OUTMODE == 1) {
                if (gcol < 128) {
                    uint2 pk;
                    pk.x = cvt2(v.x, v.y);
                    pk.y = cvt2(v.z, v.w);
                    *(uint2*)((ushort_t*)O1 + (size_t)rg * ld1 + gcol) = pk;
                } else {
                    *(float4*)(O2 + (size_t)rg * ld2 + (gcol - 128)) = v;
                }
            } else {
                if (gcol < colsplit)
                    *(float4*)((float*)O1 + (size_t)rg * ld1 + gcol) = v;
                else
                    *(float4*)(O2 + (size_t)rg * ld2 + (gcol - colsplit)) = v;
            }
        }
    }
}

// ================= weight prep =================
__global__ __launch_bounds__(128) void prep2(
    const float* __restrict__ Wa, const float* __restrict__ Wb, ushort_t* __restrict__ dst)
{
    int c = blockIdx.x, k = threadIdx.x;
    const float* W = (c < 128) ? Wa : Wb;
    int cc = c & 127;
    dst[c * 128 + k] = f2bf(W[k * 128 + cc]);
}

// conv panel: cols 0-127 = W^T, 128-131 el folds (W@al), 132-135 er folds
__global__ __launch_bounds__(128) void prep_conv(
    const float* __restrict__ W, const float* __restrict__ al, const float* __restrict__ ar,
    ushort_t* __restrict__ dst)
{
    int c = blockIdx.x, k = threadIdx.x;
    float v;
    if (c < 128) {
        v = W[k * 128 + c];
    } else {
        int idx = c - 128;
        int g = idx & 3;
        const float* a = (idx < 4) ? al : ar;
        float s = 0.f;
        for (int d = 0; d < 32; ++d) s += W[k * 128 + g * 32 + d] * a[g * 32 + d];
        v = s;
    }
    dst[c * 128 + k] = f2bf(v);
}

// ================= binned CSR build =================
// edge idx -> (src, global dst node)
static __device__ __forceinline__ void edge_decode(
    int idx, const int* __restrict__ src0, const int* __restrict__ dst0,
    const int* __restrict__ src1, const int* __restrict__ dst1,
    int& src, int& gnode)
{
    if (idx < 3 * E0) {
        src = src0[idx];
        gnode = (idx / E0) * N1 + dst0[idx];
    } else {
        int k = idx - 3 * E0;
        src = src1[k];
        gnode = 3 * N1 + (k / E1) * N2 + dst1[k];
    }
}

// Pass A: bin edges into per-bucket arenas (packed (src<<9)|local_dst).
// LDS-aggregated counts -> one global atomic per (block, nonempty bucket).
__global__ __launch_bounds__(256) void bin_pass(
    const int* __restrict__ src0, const int* __restrict__ dst0,
    const int* __restrict__ src1, const int* __restrict__ dst1,
    int* __restrict__ bcur, uint_t* __restrict__ tmp)
{
    __shared__ int lcnt[512];
    __shared__ int lbase[512];
    const int tid = threadIdx.x;
    const int e0 = blockIdx.x * 4096;
    for (int t = tid; t < 512; t += 256) lcnt[t] = 0;
    __syncthreads();
    #pragma unroll
    for (int i = 0; i < 16; ++i) {
        int idx = e0 + i * 256 + tid;
        if (idx < NE_ALL) {
            int s, g;
            edge_decode(idx, src0, dst0, src1, dst1, s, g);
            atomicAdd(&lcnt[g >> 9], 1);
        }
    }
    __syncthreads();
    for (int t = tid; t < 512; t += 256) {
        int c = lcnt[t];
        lbase[t] = c ? atomicAdd(&bcur[t], c) : 0;
        lcnt[t] = 0;
    }
    __syncthreads();
    #pragma unroll
    for (int i = 0; i < 16; ++i) {
        int idx = e0 + i * 256 + tid;
        if (idx < NE_ALL) {
            int s, g;
            edge_decode(idx, src0, dst0, src1, dst1, s, g);
            int b = g >> 9;
            int p = lbase[b] + atomicAdd(&lcnt[b], 1);
            if (p < BCAP)
                tmp[(size_t)b * BCAP + p] = (uint_t)((s << 9) | (g & 511));
        }
    }
}

// exclusive scan of bucket sizes
__global__ __launch_bounds__(512) void bucket_scan(
    const int* __restrict__ bcur, int* __restrict__ bbase)
{
    __shared__ int s[512];
    int t = threadIdx.x;
    int v = (t < NBUCK) ? bcur[t] : 0;
    s[t] = v;
    __syncthreads();
    for (int off = 1; off < 512; off <<= 1) {
        int x = (t >= off) ? s[t - off] : 0;
        __syncthreads();
        s[t] += x;
        __syncthreads();
    }
    bbase[t] = s[t] - v;
}

// Pass B: per bucket: LDS count -> LDS scan -> write offs (coalesced) and
// scatter csr into the bucket's dense contiguous region.
__global__ __launch_bounds__(256) void build_pass(
    const int* __restrict__ bcur, const int* __restrict__ bbase,
    const uint_t* __restrict__ tmp, int* __restrict__ offs, int* __restrict__ csr)
{
    __shared__ int cnt[512];
    __shared__ int offl[512];
    __shared__ int ps[256];
    const int tid = threadIdx.x;
    const int b = blockIdx.x;
    int nE = bcur[b];
    if (nE > BCAP) nE = BCAP;
    const int base = bbase[b];
    const int node0 = b * BNODE;
    const uint_t* tp = tmp + (size_t)b * BCAP;

    for (int t = tid; t < 512; t += 256) cnt[t] = 0;
    __syncthreads();
    for (int i = tid; i < nE; i += 256)
        atomicAdd(&cnt[tp[i] & 511], 1);
    __syncthreads();
    // exclusive scan over 512 via pair-sum + 256-scan
    int a0 = cnt[2 * tid], a1 = cnt[2 * tid + 1];
    ps[tid] = a0 + a1;
    __syncthreads();
    for (int off = 1; off < 256; off <<= 1) {
        int x = (tid >= off) ? ps[tid - off] : 0;
        __syncthreads();
        ps[tid] += x;
        __syncthreads();
    }
    int ex = ps[tid] - (a0 + a1);
    offl[2 * tid] = ex;
    offl[2 * tid + 1] = ex + a0;
    __syncthreads();
    for (int t = tid; t < BNODE; t += 256) {
        int gn = node0 + t;
        if (gn < N_TOT) offs[gn] = base + offl[t];
    }
    if (b == NBUCK - 1 && tid == 0) offs[N_TOT] = base + nE;
    for (int t = tid; t < 512; t += 256) cnt[t] = 0;
    __syncthreads();
    for (int i = tid; i < nE; i += 256) {
        uint_t pk = tp[i];
        int ld = pk & 511;
        int p = atomicAdd(&cnt[ld], 1);
        csr[base + offl[ld] + p] = (int)(pk >> 9);
    }
}

// ================= softmax gather (bf16 P, elr f32 [n][8]) =================
__global__ __launch_bounds__(256) void gat_gather3(
    const int* __restrict__ csrc, const int* __restrict__ offs, int nodeBase,
    const float* __restrict__ elr, const ushort_t* __restrict__ P,
    float* __restrict__ out)
{
    __shared__ float4 accs[8][32];
    __shared__ float reds[8][32];
    int node = blockIdx.x;
    int t = threadIdx.x;
    int lane = t & 31;
    int slot = t >> 5;
    int g = lane >> 3;
    int beg = offs[nodeBase + node], end = offs[nodeBase + node + 1];
    float erg = elr[(size_t)node * 8 + 4 + g];
    float den = 0.f;
    float4 acc = make_float4(0.f, 0.f, 0.f, 0.f);
    for (int i = beg + slot; i < end; i += 8) {
        int s = csrc[i];
        float w = __expf(lrelu(elr[(size_t)s * 8 + g] + erg, 0.2f));
        ushort4 p = *(const ushort4*)(P + (size_t)s * 128 + lane * 4);
        den += w;
        acc.x += w * bf2f(p.x); acc.y += w * bf2f(p.y);
        acc.z += w * bf2f(p.z); acc.w += w * bf2f(p.w);
    }
    reds[slot][lane] = den;
    accs[slot][lane] = acc;
    __syncthreads();
    if (slot < 4) {
        reds[slot][lane] += reds[slot + 4][lane];
        float4 b = accs[slot + 4][lane];
        accs[slot][lane].x += b.x; accs[slot][lane].y += b.y;
        accs[slot][lane].z += b.z; accs[slot][lane].w += b.w;
    }
    __syncthreads();
    if (slot < 2) {
        reds[slot][lane] += reds[slot + 2][lane];
        float4 b = accs[slot + 2][lane];
        accs[slot][lane].x += b.x; accs[slot][lane].y += b.y;
        accs[slot][lane].z += b.z; accs[slot][lane].w += b.w;
    }
    __syncthreads();
    if (slot == 0) {
        float d = reds[0][lane] + reds[1][lane];
        float4 a0 = accs[0][lane], a1 = accs[1][lane];
        float inv = (end > beg) ? 1.f / d : 0.f;
        float4 o;
        o.x = lrelu((a0.x + a1.x) * inv, 0.01f);
        o.y = lrelu((a0.y + a1.y) * inv, 0.01f);
        o.z = lrelu((a0.z + a1.z) * inv, 0.01f);
        o.w = lrelu((a0.w + a1.w) * inv, 0.01f);
        ((float4*)(out + (size_t)node * 128))[lane] = o;
    }
}

// ================= gated attention combine =================
template <int K>
__global__ __launch_bounds__(256) void attn_combine2(
    const float* __restrict__ grv, const float* __restrict__ gl,
    const float* __restrict__ aW, int n, float* __restrict__ out1)
{
    int node = blockIdx.x * 2 + (threadIdx.x >> 7);
    int tid = threadIdx.x & 127;
    if (node >= n) return;
    float aw = aW[tid & 15];
    float glv = gl[(size_t)node * 128 + tid];
    float e[K];
    #pragma unroll
    for (int k = 0; k < K; ++k) {
        float z = lrelu(glv + grv[((size_t)node * K + k) * 256 + tid], 0.01f);
        float p = z * aw;
        p += __shfl_xor(p, 1);
        p += __shfl_xor(p, 2);
        p += __shfl_xor(p, 4);
        p += __shfl_xor(p, 8);
        e[k] = p;
    }
    float m = e[0];
    #pragma unroll
    for (int k = 1; k < K; ++k) m = fmaxf(m, e[k]);
    float s = 0.f, w[K];
    #pragma unroll
    for (int k = 0; k < K; ++k) { w[k] = __expf(e[k] - m); s += w[k]; }
    float inv = 1.f / s;
    float acc = 0.f;
    #pragma unroll
    for (int k = 0; k < K; ++k)
        acc += (w[k] * inv) * grv[((size_t)node * K + k) * 256 + 128 + tid];
    out1[(size_t)node * 128 + tid] = lrelu(acc, 0.01f);
}

// ================= final linear 128 -> 2 =================
__global__ __launch_bounds__(256) void lin_kernel(
    const float* __restrict__ H, const float* __restrict__ W,
    const float* __restrict__ b, float* __restrict__ out, int n)
{
    int idx = blockIdx.x * 256 + threadIdx.x;
    int node = idx >> 1, c = idx & 1;
    if (node >= n) return;
    float acc = 0.f;
    for (int k = 0; k < 128; ++k)
        acc += H[(size_t)node * 128 + k] * W[k * 2 + c];
    out[(size_t)node * 2 + c] = acc + b[c];
}

extern "C" void kernel_launch(void* const* d_in, const int* in_sizes, int n_in,
                              void* d_out, int out_size, void* d_ws, size_t ws_size,
                              hipStream_t stream)
{
    (void)in_sizes; (void)n_in; (void)out_size; (void)ws_size;
    const float* x       = (const float*)d_in[0];
    const int*   src0    = (const int*)d_in[1];
    const int*   dst0    = (const int*)d_in[2];
    const int*   src1    = (const int*)d_in[3];
    const int*   dst1    = (const int*)d_in[4];
    const float* conv_W  = (const float*)d_in[5];
    const float* conv_al = (const float*)d_in[6];
    const float* conv_ar = (const float*)d_in[7];
    const float* feat_W  = (const float*)d_in[8];
    const float* feat_b  = (const float*)d_in[9];
    const float* relWl_W = (const float*)d_in[10];
    const float* relWl_b = (const float*)d_in[11];
    const float* relWr_W = (const float*)d_in[12];
    const float* relWr_b = (const float*)d_in[13];
    const float* relP_W  = (const float*)d_in[14];
    const float* relP_b  = (const float*)d_in[15];
    const float* rela_W  = (const float*)d_in[16];
    const float* proj_W  = (const float*)d_in[18];
    const float* proj_b  = (const float*)d_in[19];
    const float* hopWl_W = (const float*)d_in[20];
    const float* hopWl_b = (const float*)d_in[21];
    const float* hopWr_W = (const float*)d_in[22];
    const float* hopWr_b = (const float*)d_in[23];
    const float* hopP_W  = (const float*)d_in[24];
    const float* hopP_b  = (const float*)d_in[25];
    const float* hopa_W  = (const float*)d_in[26];
    const float* lin_W   = (const float*)d_in[28];
    const float* lin_b   = (const float*)d_in[29];
    float* out = (float*)d_out;

    // ---- workspace layout (~244 MB) ----
    char* base = (char*)d_ws;
    size_t off = 0;
    auto alloc = [&](size_t bytes) -> void* {
        void* p = base + off;
        off += (bytes + 255) & ~(size_t)255;
        return p;
    };
    ushort_t* P     = (ushort_t*)alloc((size_t)N0 * 128 * 2);   // bf16 conv proj
    float* elr      = (float*)alloc((size_t)N0 * 8 * 4);        // el[0:4], er[4:8]
    float* F0       = (float*)alloc((size_t)N1 * 128 * 4);
    float* F1       = (float*)alloc((size_t)N1 * 128 * 4);
    float* F2       = (float*)alloc((size_t)N1 * 128 * 4);
    float* F3       = (float*)alloc((size_t)N1 * 128 * 4);
    float* glbuf    = (float*)alloc((size_t)N1 * 128 * 4);
    float* h1       = (float*)alloc((size_t)N1 * 128 * 4);
    float* grv      = (float*)alloc((size_t)N1 * 256 * 4);      // 51.2 MB
    int*   csr_all  = (int*)alloc((size_t)NE_ALL * 4);
    int*   offs     = (int*)alloc((size_t)(N_TOT + 1) * 4);
    int*   bcur     = (int*)alloc(512 * 4);
    int*   bbase    = (int*)alloc(512 * 4);
    ushort_t* pconv[6];
    for (int i = 0; i < 6; ++i) pconv[i] = (ushort_t*)alloc(136 * 128 * 2);
    ushort_t* p2L0 = (ushort_t*)alloc(256 * 128 * 2);
    ushort_t* p2L1 = (ushort_t*)alloc(256 * 128 * 2);
    ushort_t* pE   = (ushort_t*)alloc(256 * 128 * 2);
    ushort_t* pF0  = (ushort_t*)alloc(256 * 128 * 2);
    ushort_t* pF1  = (ushort_t*)alloc(256 * 128 * 2);
    ushort_t* pG   = (ushort_t*)alloc(256 * 128 * 2);

    float* glhop = (float*)((char*)grv + 38400000);  // hop grv uses 38.4 MB
    float* h2    = F1;
    float* hopp0 = F0;
    float* hout  = glbuf;
    uint_t* tmp  = (uint_t*)grv;   // 21.6 MB bin arenas; CSR build precedes grv use

    // ---- weight prep ----
    for (int i = 0; i < 6; ++i)
        prep_conv<<<136, 128, 0, stream>>>(conv_W + (size_t)i * 16384,
                                           conv_al + (size_t)i * 128,
                                           conv_ar + (size_t)i * 128, pconv[i]);
    prep2<<<256, 128, 0, stream>>>(feat_W, relWl_W, p2L0);
    prep2<<<256, 128, 0, stream>>>(feat_W + 16384, relWl_W + 16384, p2L1);
    prep2<<<256, 128, 0, stream>>>(proj_W, hopWl_W, pE);
    prep2<<<256, 128, 0, stream>>>(relWr_W, relP_W, pF0);
    prep2<<<256, 128, 0, stream>>>(relWr_W + 16384, relP_W + 16384, pF1);
    prep2<<<256, 128, 0, stream>>>(hopWr_W, hopP_W, pG);

    // ---- binned CSR build ----
    hipMemsetAsync(bcur, 0, 512 * 4, stream);
    bin_pass<<<(NE_ALL + 4095) / 4096, 256, 0, stream>>>(src0, dst0, src1, dst1, bcur, tmp);
    bucket_scan<<<1, 512, 0, stream>>>(bcur, bbase);
    build_pass<<<NBUCK, 256, 0, stream>>>(bcur, bbase, tmp, offs, csr_all);

    const int CH = 12500;

    // ---- layer 0 ----
    for (int j = 0; j < 3; ++j) {
        gemm_bf16<9, 1, 1><<<dim3((N0 + 127) / 128, 1), 256, 0, stream>>>(
            x, x, x, x, N0, pconv[j], 136, nullptr, nullptr, 128, 1.f, 1.f,
            P, 128, elr, 8);
        float* Fj = (j == 0) ? F0 : (j == 1) ? F1 : F2;
        gat_gather3<<<N1, 256, 0, stream>>>(csr_all, offs, j * N1, elr, P, Fj);
    }
    gemm_bf16<8, 1, 0><<<dim3((N1 + 127) / 128, 2), 256, 0, stream>>>(
        x, x, x, x, N1, p2L0, 256, feat_b, relWl_b, 128, 0.01f, 1.f,
        F3, 128, glbuf, 128);
    for (int c = 0; c < N1; c += CH) {
        gemm_bf16<8, 4, 0><<<dim3((CH * 4 + 127) / 128, 2), 256, 0, stream>>>(
            F0 + (size_t)c * 128, F1 + (size_t)c * 128, F2 + (size_t)c * 128, F3 + (size_t)c * 128,
            CH, pF0, 256, relWr_b, relP_b, 128, 1.f, 1.f,
            grv, 256, grv + 128, 256);
        attn_combine2<4><<<CH / 2, 256, 0, stream>>>(
            grv, glbuf + (size_t)c * 128, rela_W, CH, h1 + (size_t)c * 128);
    }

    // ---- layer 1 ----
    for (int j = 0; j < 3; ++j) {
        gemm_bf16<9, 1, 1><<<dim3((N1 + 127) / 128, 1), 256, 0, stream>>>(
            h1, h1, h1, h1, N1, pconv[3 + j], 136, nullptr, nullptr, 128, 1.f, 1.f,
            P, 128, elr, 8);
        float* Fj = (j == 0) ? F0 : (j == 1) ? F1 : F2;
        gat_gather3<<<N2, 256, 0, stream>>>(csr_all, offs, 3 * N1 + j * N2, elr, P, Fj);
    }
    gemm_bf16<8, 1, 0><<<dim3((N2 + 127) / 128, 2), 256, 0, stream>>>(
        h1, h1, h1, h1, N2, p2L1, 256, feat_b + 128, relWl_b + 128, 128, 0.01f, 1.f,
        F3, 128, glbuf, 128);
    for (int c = 0; c < N2; c += CH) {
        gemm_bf16<8, 4, 0><<<dim3((CH * 4 + 127) / 128, 2), 256, 0, stream>>>(
            F0 + (size_t)c * 128, F1 + (size_t)c * 128, F2 + (size_t)c * 128, F3 + (size_t)c * 128,
            CH, pF1, 256, relWr_b + 128, relP_b + 128, 128, 1.f, 1.f,
            grv, 256, grv + 128, 256);
        attn_combine2<4><<<CH / 2, 256, 0, stream>>>(
            grv, glbuf + (size_t)c * 128, rela_W + 16, CH, h2 + (size_t)c * 128);
    }

    // ---- proj + hop gl ----
    gemm_bf16<8, 1, 0><<<dim3((N2 + 127) / 128, 2), 256, 0, stream>>>(
        x, x, x, x, N2, pE, 256, proj_b, hopWl_b, 128, 1.f, 1.f,
        hopp0, 128, glhop, 128);

    // ---- hop attention over [proj, h1[:N2], h2] ----
    for (int c = 0; c < N2; c += CH) {
        gemm_bf16<8, 3, 0><<<dim3((CH * 3 + 127) / 128, 2), 256, 0, stream>>>(
            hopp0 + (size_t)c * 128, h1 + (size_t)c * 128, h2 + (size_t)c * 128, hopp0,
            CH, pG, 256, hopWr_b, hopP_b, 128, 1.f, 1.f,
            grv, 256, grv + 128, 256);
        attn_combine2<3><<<CH / 2, 256, 0, stream>>>(
            grv, glhop + (size_t)c * 128, hopa_W, CH, hout + (size_t)c * 128);
    }

    // ---- final linear ----
    lin_kernel<<<(N2 * 2 + 255) / 256, 256, 0, stream>>>(hout, lin_W, lin_b, out, N2);
}

// Round 8
// 659.882 us; speedup vs baseline: 3.8721x; 1.2674x over previous
//
#include <hip/hip_runtime.h>

#define N0 100000
#define N1 50000
#define N2 25000
#define E0 500000
#define E1 250000
#define N_TOT (3 * N1 + 3 * N2)
#define NE_ALL (3 * E0 + 3 * E1)
#define BNODE 512
#define NBUCK ((N_TOT + BNODE - 1) / BNODE)   // 440
#define BCAP 12288

typedef __attribute__((ext_vector_type(8))) short short8;
typedef __attribute__((ext_vector_type(4))) float f32x4;
typedef unsigned short ushort_t;
typedef unsigned int uint_t;

static __device__ __forceinline__ float lrelu(float x, float s) {
    return x >= 0.f ? x : s * x;
}

static __device__ __forceinline__ ushort_t f2bf(float f) {
    union { float f; uint_t u; } v; v.f = f;
    uint_t r = v.u + 0x7FFFu + ((v.u >> 16) & 1u);
    return (ushort_t)(r >> 16);
}

static __device__ __forceinline__ float bf_lo(uint_t u) {
    union { uint_t i; float f; } v; v.i = u << 16;
    return v.f;
}
static __device__ __forceinline__ float bf_hi(uint_t u) {
    union { uint_t i; float f; } v; v.i = u & 0xFFFF0000u;
    return v.f;
}

static __device__ __forceinline__ uint_t cvt2(float lo, float hi) {
    uint_t r;
    asm("v_cvt_pk_bf16_f32 %0, %1, %2" : "=v"(r) : "v"(lo), "v"(hi));
    return r;
}

// ================= MFMA GEMM =================
// 256 thr = 4 waves; tile 128 rows x CT*16 cols. A: f32 global (PLANES
// row-interleaved), cvt bf16 in-reg. B: bf16 [col][k] LDS panel (XOR swizzle).
// OUTMODE 0: f32 outputs, GLOBAL col < colsplit -> O1 else O2 (LDS transpose).
// OUTMODE 1 (conv): col<128 -> bf16 O1 (P), col>=128 -> f32 O2 (elr, ld2=8).
// OUTMODE 2 (attn e/w): PLANES=4. No C store. e = red16(lrelu(gl+gr)*aW),
//   softmax over k in LDS -> w[node][k*8+head] (O1). kreal masks dummy planes.
// OUTMODE 3 (attn v-combine): PLANES=4. LDS transpose; h[node] =
//   lrelu(sum_k w[node,k,head]*v_row, 0.01) -> O1. w read from O2.
template <int CT, int PLANES, int OUTMODE>
__global__ __launch_bounds__(256) void gemm_bf16(
    const float* __restrict__ A0, const float* __restrict__ A1,
    const float* __restrict__ A2, const float* __restrict__ A3,
    int nodes, const ushort_t* __restrict__ Bt, int cols,
    const float* __restrict__ biasA, const float* __restrict__ biasB,
    int colsplit, float slopeA, float slopeB,
    void* __restrict__ O1, int ld1, float* __restrict__ O2, int ld2,
    const float* __restrict__ glp, const float* __restrict__ aWp, int kreal)
{
    constexpr int BCOLS = CT * 16;
    constexpr int CSTR = BCOLS + 4;
    constexpr int SH_B = BCOLS * 256;
    constexpr int SH_C = 64 * CSTR * 4;
    constexpr int SHSZ = SH_B > SH_C ? SH_B : SH_C;
    __shared__ char sh[SHSZ];
    float* Cs = (float*)sh;

    const int Mrows = nodes * PLANES;
    const int row0 = blockIdx.x * 128;
    const int cbase = blockIdx.y * BCOLS;
    const int tid = threadIdx.x;

    // ---- stage B panel (swizzled) ----
    for (int cl = tid >> 1; cl < BCOLS; cl += 128) {
        int c = cbase + cl;
        int kh = (tid & 1) * 64;
        if (c < cols) {
            const uint4* srcp = (const uint4*)(Bt + (size_t)c * 128 + kh);
            #pragma unroll
            for (int i = 0; i < 8; ++i) {
                uint4 d = srcp[i];
                int off = cl * 256 + kh * 2 + i * 16;
                off ^= (cl & 7) << 4;
                *(uint4*)(sh + off) = d;
            }
        } else {
            #pragma unroll
            for (int i = 0; i < 8; ++i) {
                int off = cl * 256 + kh * 2 + i * 16;
                off ^= (cl & 7) << 4;
                *(uint4*)(sh + off) = make_uint4(0, 0, 0, 0);
            }
        }
    }
    __syncthreads();

    const int wv = tid >> 6;
    const int l = tid & 63;
    const int kg = l >> 4;
    const float* aptr[2];
    #pragma unroll
    for (int rt = 0; rt < 2; ++rt) {
        int rg = row0 + wv * 32 + rt * 16 + (l & 15);
        if (rg >= Mrows) rg = Mrows - 1;
        int node, pl;
        if (PLANES == 1) { node = rg; pl = 0; }
        else { node = rg / PLANES; pl = rg % PLANES; }
        const float* base = (pl == 0) ? A0 : (pl == 1) ? A1 : (pl == 2) ? A2 : A3;
        aptr[rt] = base + (size_t)node * 128 + kg * 8;
    }

    f32x4 acc[2][CT];
    #pragma unroll
    for (int a = 0; a < 2; ++a)
        #pragma unroll
        for (int b = 0; b < CT; ++b)
            #pragma unroll
            for (int q = 0; q < 4; ++q) acc[a][b][q] = 0.f;

    #pragma unroll
    for (int kt = 0; kt < 4; ++kt) {
        short8 af[2];
        #pragma unroll
        for (int rt = 0; rt < 2; ++rt) {
            const float4* p = (const float4*)(aptr[rt] + kt * 32);
            float4 x0 = p[0];
            float4 x1 = p[1];
            union { uint_t u[4]; short8 s; } u;
            u.u[0] = cvt2(x0.x, x0.y);
            u.u[1] = cvt2(x0.z, x0.w);
            u.u[2] = cvt2(x1.x, x1.y);
            u.u[3] = cvt2(x1.z, x1.w);
            af[rt] = u.s;
        }
        #pragma unroll
        for (int ct = 0; ct < CT; ++ct) {
            int off = ((ct * 16 + (l & 15)) * 256) + kt * 64 + (l >> 4) * 16;
            off ^= (l & 7) << 4;
            short8 bfr = *(const short8*)(sh + off);
            acc[0][ct] = __builtin_amdgcn_mfma_f32_16x16x32_bf16(af[0], bfr, acc[0][ct], 0, 0, 0);
            acc[1][ct] = __builtin_amdgcn_mfma_f32_16x16x32_bf16(af[1], bfr, acc[1][ct], 0, 0, 0);
        }
    }

    if (OUTMODE == 2) {
        // ---- e/w epilogue: no C store at all ----
        __syncthreads();                      // all B reads done; reuse sh
        float* e_sh = (float*)sh;             // [128][8]
        float* w_sh = e_sh + 128 * 8;         // [32][32]
        const int hh = l & 15;
        const float aw = aWp[hh];
        #pragma unroll
        for (int rt = 0; rt < 2; ++rt) {
            #pragma unroll
            for (int ct = 0; ct < CT; ++ct) {
                int col = ct * 16 + hh;
                float br_ = biasA ? biasA[col] : 0.f;
                #pragma unroll
                for (int j = 0; j < 4; ++j) {
                    int lr = wv * 32 + rt * 16 + (l >> 4) * 4 + j;
                    int node = (row0 + lr) >> 2;
                    if (node > nodes - 1) node = nodes - 1;
                    float glv = glp[(size_t)node * 128 + col];
                    float z = lrelu(glv + acc[rt][ct][j] + br_, 0.01f);
                    float p = z * aw;
                    p += __shfl_xor(p, 1);
                    p += __shfl_xor(p, 2);
                    p += __shfl_xor(p, 4);
                    p += __shfl_xor(p, 8);
                    if (hh == 0) e_sh[lr * 8 + ct] = p;
                }
            }
        }
        __syncthreads();
        {
            int nl = tid >> 3, head = tid & 7;
            float e0 = e_sh[(nl * 4 + 0) * 8 + head];
            float e1 = e_sh[(nl * 4 + 1) * 8 + head];
            float e2 = e_sh[(nl * 4 + 2) * 8 + head];
            float e3 = (kreal == 4) ? e_sh[(nl * 4 + 3) * 8 + head] : -1e30f;
            float m = fmaxf(fmaxf(e0, e1), fmaxf(e2, e3));
            float x0 = __expf(e0 - m), x1 = __expf(e1 - m), x2 = __expf(e2 - m);
            float x3 = (kreal == 4) ? __expf(e3 - m) : 0.f;
            float inv = 1.f / (x0 + x1 + x2 + x3);
            w_sh[nl * 32 + 0 * 8 + head] = x0 * inv;
            w_sh[nl * 32 + 1 * 8 + head] = x1 * inv;
            w_sh[nl * 32 + 2 * 8 + head] = x2 * inv;
            w_sh[nl * 32 + 3 * 8 + head] = x3 * inv;
        }
        __syncthreads();
        {
            int node0 = row0 >> 2;
            if (node0 + (tid >> 3) < nodes) {
                float4 v4 = *(float4*)&w_sh[tid * 4];
                *(float4*)((float*)O1 + (size_t)node0 * 32 + tid * 4) = v4;
            }
        }
        return;
    }

    if (OUTMODE == 3) {
        // ---- v-combine epilogue ----
        const float* wbuf = O2;
        const int node0 = row0 >> 2;
        #pragma unroll
        for (int rt = 0; rt < 2; ++rt) {
            __syncthreads();
            #pragma unroll
            for (int ct = 0; ct < CT; ++ct) {
                int col = ct * 16 + (l & 15);
                float bias_ = biasA ? biasA[col] : 0.f;
                int lrow = wv * 16 + (l >> 4) * 4;
                #pragma unroll
                for (int j = 0; j < 4; ++j)
                    Cs[(lrow + j) * CSTR + col] = acc[rt][ct][j] + bias_;
            }
            __syncthreads();
            #pragma unroll
            for (int it = tid; it < 512; it += 256) {
                int nidx = it >> 5;
                int c4 = it & 31;
                int nl = rt * 4 + (nidx >> 2) * 8 + (nidx & 3);
                int gn = node0 + nl;
                if (gn >= nodes) continue;
                int head = c4 >> 2;
                float4 o = make_float4(0.f, 0.f, 0.f, 0.f);
                #pragma unroll
                for (int k = 0; k < 4; ++k) {
                    int lr = 4 * nl + k;
                    int rho = ((lr >> 5) << 4) | (lr & 15);
                    float wk = wbuf[(size_t)gn * 32 + k * 8 + head];
                    float4 v4 = *(const float4*)&Cs[rho * CSTR + c4 * 4];
                    o.x += wk * v4.x; o.y += wk * v4.y;
                    o.z += wk * v4.z; o.w += wk * v4.w;
                }
                o.x = lrelu(o.x, 0.01f); o.y = lrelu(o.y, 0.01f);
                o.z = lrelu(o.z, 0.01f); o.w = lrelu(o.w, 0.01f);
                *(float4*)((float*)O1 + (size_t)gn * 128 + c4 * 4) = o;
            }
        }
        return;
    }

    // ---- OUTMODE 0/1: LDS transpose, clean vector stores ----
    #pragma unroll
    for (int rt = 0; rt < 2; ++rt) {
        __syncthreads();
        #pragma unroll
        for (int ct = 0; ct < CT; ++ct) {
            int c = cbase + ct * 16 + (l & 15);
            float bias_ = 0.f, slope_ = 1.f;
            if (c < colsplit) {
                if (biasA) bias_ = biasA[c];
                slope_ = slopeA;
            } else if (c < cols) {
                if (biasB) bias_ = biasB[c - colsplit];
                slope_ = slopeB;
            }
            int lrow = wv * 16 + (l >> 4) * 4;
            #pragma unroll
            for (int j = 0; j < 4; ++j) {
                float v = acc[rt][ct][j] + bias_;
                v = v >= 0.f ? v : v * slope_;
                Cs[(lrow + j) * CSTR + ct * 16 + (l & 15)] = v;
            }
        }
        __syncthreads();
        for (int i = tid; i < 64 * CT * 4; i += 256) {
            int rho = i / (CT * 4);
            int c4 = i - rho * (CT * 4);
            int col = c4 * 4;
            int gcol = cbase + col;
            int rg = row0 + rt * 16 + (rho >> 4) * 32 + (rho & 15);
            if (rg >= Mrows || gcol >= cols) continue;
            float4 v = *(const float4*)&Cs[rho * CSTR + col];
            if (OUTMODE == 1) {
                if (gcol < 128) {
                    uint2 pk;
                    pk.x = cvt2(v.x, v.y);
                    pk.y = cvt2(v.z, v.w);
                    *(uint2*)((ushort_t*)O1 + (size_t)rg * ld1 + gcol) = pk;
                } else {
                    *(float4*)(O2 + (size_t)rg * ld2 + (gcol - 128)) = v;
                }
            } else {
                if (gcol < colsplit)
                    *(float4*)((float*)O1 + (size_t)rg * ld1 + gcol) = v;
                else
                    *(float4*)(O2 + (size_t)rg * ld2 + (gcol - colsplit)) = v;
            }
        }
    }
}

// ================= weight prep =================
__global__ __launch_bounds__(128) void prep2(
    const float* __restrict__ Wa, const float* __restrict__ Wb, ushort_t* __restrict__ dst)
{
    int c = blockIdx.x, k = threadIdx.x;
    const float* W = (c < 128) ? Wa : Wb;
    int cc = c & 127;
    dst[c * 128 + k] = f2bf(W[k * 128 + cc]);
}

__global__ __launch_bounds__(128) void prep_conv(
    const float* __restrict__ W, const float* __restrict__ al, const float* __restrict__ ar,
    ushort_t* __restrict__ dst)
{
    int c = blockIdx.x, k = threadIdx.x;
    float v;
    if (c < 128) {
        v = W[k * 128 + c];
    } else {
        int idx = c - 128;
        int g = idx & 3;
        const float* a = (idx < 4) ? al : ar;
        float s = 0.f;
        for (int d = 0; d < 32; ++d) s += W[k * 128 + g * 32 + d] * a[g * 32 + d];
        v = s;
    }
    dst[c * 128 + k] = f2bf(v);
}

// ================= binned CSR build =================
static __device__ __forceinline__ void edge_decode(
    int idx, const int* __restrict__ src0, const int* __restrict__ dst0,
    const int* __restrict__ src1, const int* __restrict__ dst1,
    int& src, int& gnode)
{
    if (idx < 3 * E0) {
        src = src0[idx];
        gnode = (idx / E0) * N1 + dst0[idx];
    } else {
        int k = idx - 3 * E0;
        src = src1[k];
        gnode = 3 * N1 + (k / E1) * N2 + dst1[k];
    }
}

__global__ __launch_bounds__(256) void bin_pass(
    const int* __restrict__ src0, const int* __restrict__ dst0,
    const int* __restrict__ src1, const int* __restrict__ dst1,
    int* __restrict__ bcur, uint_t* __restrict__ tmp)
{
    __shared__ int lcnt[512];
    __shared__ int lbase[512];
    const int tid = threadIdx.x;
    const int e0 = blockIdx.x * 4096;
    for (int t = tid; t < 512; t += 256) lcnt[t] = 0;
    __syncthreads();
    #pragma unroll
    for (int i = 0; i < 16; ++i) {
        int idx = e0 + i * 256 + tid;
        if (idx < NE_ALL) {
            int s, g;
            edge_decode(idx, src0, dst0, src1, dst1, s, g);
            atomicAdd(&lcnt[g >> 9], 1);
        }
    }
    __syncthreads();
    for (int t = tid; t < 512; t += 256) {
        int c = lcnt[t];
        lbase[t] = c ? atomicAdd(&bcur[t], c) : 0;
        lcnt[t] = 0;
    }
    __syncthreads();
    #pragma unroll
    for (int i = 0; i < 16; ++i) {
        int idx = e0 + i * 256 + tid;
        if (idx < NE_ALL) {
            int s, g;
            edge_decode(idx, src0, dst0, src1, dst1, s, g);
            int b = g >> 9;
            int p = lbase[b] + atomicAdd(&lcnt[b], 1);
            if (p < BCAP)
                tmp[(size_t)b * BCAP + p] = (uint_t)((s << 9) | (g & 511));
        }
    }
}

__global__ __launch_bounds__(512) void bucket_scan(
    const int* __restrict__ bcur, int* __restrict__ bbase)
{
    __shared__ int s[512];
    int t = threadIdx.x;
    int v = (t < NBUCK) ? bcur[t] : 0;
    s[t] = v;
    __syncthreads();
    for (int off = 1; off < 512; off <<= 1) {
        int x = (t >= off) ? s[t - off] : 0;
        __syncthreads();
        s[t] += x;
        __syncthreads();
    }
    bbase[t] = s[t] - v;
}

__global__ __launch_bounds__(256) void build_pass(
    const int* __restrict__ bcur, const int* __restrict__ bbase,
    const uint_t* __restrict__ tmp, int* __restrict__ offs, int* __restrict__ csr)
{
    __shared__ int cnt[512];
    __shared__ int offl[512];
    __shared__ int ps[256];
    const int tid = threadIdx.x;
    const int b = blockIdx.x;
    int nE = bcur[b];
    if (nE > BCAP) nE = BCAP;
    const int base = bbase[b];
    const int node0 = b * BNODE;
    const uint_t* tp = tmp + (size_t)b * BCAP;

    for (int t = tid; t < 512; t += 256) cnt[t] = 0;
    __syncthreads();
    for (int i = tid; i < nE; i += 256)
        atomicAdd(&cnt[tp[i] & 511], 1);
    __syncthreads();
    int a0 = cnt[2 * tid], a1 = cnt[2 * tid + 1];
    ps[tid] = a0 + a1;
    __syncthreads();
    for (int off = 1; off < 256; off <<= 1) {
        int x = (tid >= off) ? ps[tid - off] : 0;
        __syncthreads();
        ps[tid] += x;
        __syncthreads();
    }
    int ex = ps[tid] - (a0 + a1);
    offl[2 * tid] = ex;
    offl[2 * tid + 1] = ex + a0;
    __syncthreads();
    for (int t = tid; t < BNODE; t += 256) {
        int gn = node0 + t;
        if (gn < N_TOT) offs[gn] = base + offl[t];
    }
    if (b == NBUCK - 1 && tid == 0) offs[N_TOT] = base + nE;
    for (int t = tid; t < 512; t += 256) cnt[t] = 0;
    __syncthreads();
    for (int i = tid; i < nE; i += 256) {
        uint_t pk = tp[i];
        int ld = pk & 511;
        int p = atomicAdd(&cnt[ld], 1);
        csr[base + offl[ld] + p] = (int)(pk >> 9);
    }
}

// ====== softmax gather: one WAVE per node, 4 slots x 16 lanes, no LDS ======
__global__ __launch_bounds__(256) void gat_gather4(
    const int* __restrict__ csrc, const int* __restrict__ offs, int nodeBase,
    int nNodes, const float* __restrict__ elr, const ushort_t* __restrict__ P,
    float* __restrict__ out)
{
    const int wv = threadIdx.x >> 6;
    const int node = blockIdx.x * 4 + wv;
    if (node >= nNodes) return;
    const int l = threadIdx.x & 63;
    const int lane16 = l & 15;
    const int slot = l >> 4;
    const int g = lane16 >> 2;            // head for cols lane16*8..+7
    const int beg = offs[nodeBase + node], end = offs[nodeBase + node + 1];
    const float erg = elr[(size_t)node * 8 + 4 + g];
    float den = 0.f;
    float a0 = 0.f, a1 = 0.f, a2 = 0.f, a3 = 0.f;
    float a4 = 0.f, a5 = 0.f, a6 = 0.f, a7 = 0.f;
    for (int i = beg + slot; i < end; i += 4) {
        int s = csrc[i];
        float w = __expf(lrelu(elr[(size_t)s * 8 + g] + erg, 0.2f));
        uint4 d = *(const uint4*)(P + (size_t)s * 128 + lane16 * 8);
        den += w;
        a0 += w * bf_lo(d.x); a1 += w * bf_hi(d.x);
        a2 += w * bf_lo(d.y); a3 += w * bf_hi(d.y);
        a4 += w * bf_lo(d.z); a5 += w * bf_hi(d.z);
        a6 += w * bf_lo(d.w); a7 += w * bf_hi(d.w);
    }
    #pragma unroll
    for (int m = 16; m <= 32; m <<= 1) {
        den += __shfl_xor(den, m);
        a0 += __shfl_xor(a0, m); a1 += __shfl_xor(a1, m);
        a2 += __shfl_xor(a2, m); a3 += __shfl_xor(a3, m);
        a4 += __shfl_xor(a4, m); a5 += __shfl_xor(a5, m);
        a6 += __shfl_xor(a6, m); a7 += __shfl_xor(a7, m);
    }
    if (slot == 0) {
        float inv = (end > beg) ? 1.f / den : 0.f;
        float4 o0, o1;
        o0.x = lrelu(a0 * inv, 0.01f); o0.y = lrelu(a1 * inv, 0.01f);
        o0.z = lrelu(a2 * inv, 0.01f); o0.w = lrelu(a3 * inv, 0.01f);
        o1.x = lrelu(a4 * inv, 0.01f); o1.y = lrelu(a5 * inv, 0.01f);
        o1.z = lrelu(a6 * inv, 0.01f); o1.w = lrelu(a7 * inv, 0.01f);
        float* op = out + (size_t)node * 128 + lane16 * 8;
        *(float4*)op = o0;
        *(float4*)(op + 4) = o1;
    }
}

// ================= final linear 128 -> 2 =================
__global__ __launch_bounds__(256) void lin_kernel(
    const float* __restrict__ H, const float* __restrict__ W,
    const float* __restrict__ b, float* __restrict__ out, int n)
{
    int idx = blockIdx.x * 256 + threadIdx.x;
    int node = idx >> 1, c = idx & 1;
    if (node >= n) return;
    float acc = 0.f;
    for (int k = 0; k < 128; ++k)
        acc += H[(size_t)node * 128 + k] * W[k * 2 + c];
    out[(size_t)node * 2 + c] = acc + b[c];
}

extern "C" void kernel_launch(void* const* d_in, const int* in_sizes, int n_in,
                              void* d_out, int out_size, void* d_ws, size_t ws_size,
                              hipStream_t stream)
{
    (void)in_sizes; (void)n_in; (void)out_size; (void)ws_size;
    const float* x       = (const float*)d_in[0];
    const int*   src0    = (const int*)d_in[1];
    const int*   dst0    = (const int*)d_in[2];
    const int*   src1    = (const int*)d_in[3];
    const int*   dst1    = (const int*)d_in[4];
    const float* conv_W  = (const float*)d_in[5];
    const float* conv_al = (const float*)d_in[6];
    const float* conv_ar = (const float*)d_in[7];
    const float* feat_W  = (const float*)d_in[8];
    const float* feat_b  = (const float*)d_in[9];
    const float* relWl_W = (const float*)d_in[10];
    const float* relWl_b = (const float*)d_in[11];
    const float* relWr_W = (const float*)d_in[12];
    const float* relWr_b = (const float*)d_in[13];
    const float* relP_W  = (const float*)d_in[14];
    const float* relP_b  = (const float*)d_in[15];
    const float* rela_W  = (const float*)d_in[16];
    const float* proj_W  = (const float*)d_in[18];
    const float* proj_b  = (const float*)d_in[19];
    const float* hopWl_W = (const float*)d_in[20];
    const float* hopWl_b = (const float*)d_in[21];
    const float* hopWr_W = (const float*)d_in[22];
    const float* hopWr_b = (const float*)d_in[23];
    const float* hopP_W  = (const float*)d_in[24];
    const float* hopP_b  = (const float*)d_in[25];
    const float* hopa_W  = (const float*)d_in[26];
    const float* lin_W   = (const float*)d_in[28];
    const float* lin_b   = (const float*)d_in[29];
    float* out = (float*)d_out;

    // ---- workspace layout (~212 MB) ----
    char* base = (char*)d_ws;
    size_t off = 0;
    auto alloc = [&](size_t bytes) -> void* {
        void* p = base + off;
        off += (bytes + 255) & ~(size_t)255;
        return p;
    };
    ushort_t* P     = (ushort_t*)alloc((size_t)N0 * 128 * 2);
    float* elr      = (float*)alloc((size_t)N0 * 8 * 4);
    float* F0       = (float*)alloc((size_t)N1 * 128 * 4);
    float* F1       = (float*)alloc((size_t)N1 * 128 * 4);
    float* F2       = (float*)alloc((size_t)N1 * 128 * 4);
    float* F3       = (float*)alloc((size_t)N1 * 128 * 4);
    float* glbuf    = (float*)alloc((size_t)N1 * 128 * 4);
    float* h1       = (float*)alloc((size_t)N1 * 128 * 4);
    float* wbuf     = (float*)alloc((size_t)N1 * 32 * 4);
    float* glhop    = (float*)alloc((size_t)N2 * 128 * 4);
    int*   csr_all  = (int*)alloc((size_t)NE_ALL * 4);
    int*   offs     = (int*)alloc((size_t)(N_TOT + 1) * 4);
    int*   bcur     = (int*)alloc(512 * 4);
    int*   bbase    = (int*)alloc(512 * 4);
    ushort_t* pconv[6];
    for (int i = 0; i < 6; ++i) pconv[i] = (ushort_t*)alloc(136 * 128 * 2);
    ushort_t* p2L0 = (ushort_t*)alloc(256 * 128 * 2);
    ushort_t* p2L1 = (ushort_t*)alloc(256 * 128 * 2);
    ushort_t* pE   = (ushort_t*)alloc(256 * 128 * 2);
    ushort_t* pF0  = (ushort_t*)alloc(256 * 128 * 2);
    ushort_t* pF1  = (ushort_t*)alloc(256 * 128 * 2);
    ushort_t* pG   = (ushort_t*)alloc(256 * 128 * 2);

    float* h2    = F1;          // written by L1 v-GEMM (block-local rows only)
    float* hopp0 = F0;          // proj plane, after L1 attn done
    float* hout  = glbuf;       // glbuf dead after L1 e-GEMM
    uint_t* tmp  = (uint_t*)F0; // 21.6 MB bin arenas; CSR build precedes F writes

    // ---- weight prep ----
    for (int i = 0; i < 6; ++i)
        prep_conv<<<136, 128, 0, stream>>>(conv_W + (size_t)i * 16384,
                                           conv_al + (size_t)i * 128,
                                           conv_ar + (size_t)i * 128, pconv[i]);
    prep2<<<256, 128, 0, stream>>>(feat_W, relWl_W, p2L0);
    prep2<<<256, 128, 0, stream>>>(feat_W + 16384, relWl_W + 16384, p2L1);
    prep2<<<256, 128, 0, stream>>>(proj_W, hopWl_W, pE);
    prep2<<<256, 128, 0, stream>>>(relWr_W, relP_W, pF0);
    prep2<<<256, 128, 0, stream>>>(relWr_W + 16384, relP_W + 16384, pF1);
    prep2<<<256, 128, 0, stream>>>(hopWr_W, hopP_W, pG);

    // ---- binned CSR build ----
    hipMemsetAsync(bcur, 0, 512 * 4, stream);
    bin_pass<<<(NE_ALL + 4095) / 4096, 256, 0, stream>>>(src0, dst0, src1, dst1, bcur, tmp);
    bucket_scan<<<1, 512, 0, stream>>>(bcur, bbase);
    build_pass<<<NBUCK, 256, 0, stream>>>(bcur, bbase, tmp, offs, csr_all);

    // ---- layer 0 ----
    for (int j = 0; j < 3; ++j) {
        gemm_bf16<9, 1, 1><<<dim3((N0 + 127) / 128, 1), 256, 0, stream>>>(
            x, x, x, x, N0, pconv[j], 136, nullptr, nullptr, 128, 1.f, 1.f,
            P, 128, elr, 8, nullptr, nullptr, 0);
        float* Fj = (j == 0) ? F0 : (j == 1) ? F1 : F2;
        gat_gather4<<<(N1 + 3) / 4, 256, 0, stream>>>(csr_all, offs, j * N1, N1, elr, P, Fj);
    }
    gemm_bf16<8, 1, 0><<<dim3((N1 + 127) / 128, 2), 256, 0, stream>>>(
        x, x, x, x, N1, p2L0, 256, feat_b, relWl_b, 128, 0.01f, 1.f,
        F3, 128, glbuf, 128, nullptr, nullptr, 0);
    gemm_bf16<8, 4, 2><<<dim3((N1 * 4 + 127) / 128, 1), 256, 0, stream>>>(
        F0, F1, F2, F3, N1, pF0, 128, relWr_b, nullptr, 128, 1.f, 1.f,
        wbuf, 0, nullptr, 0, glbuf, rela_W, 4);
    gemm_bf16<8, 4, 3><<<dim3((N1 * 4 + 127) / 128, 1), 256, 0, stream>>>(
        F0, F1, F2, F3, N1, pF0 + 16384, 128, relP_b, nullptr, 128, 1.f, 1.f,
        h1, 128, wbuf, 0, nullptr, nullptr, 0);

    // ---- layer 1 ----
    for (int j = 0; j < 3; ++j) {
        gemm_bf16<9, 1, 1><<<dim3((N1 + 127) / 128, 1), 256, 0, stream>>>(
            h1, h1, h1, h1, N1, pconv[3 + j], 136, nullptr, nullptr, 128, 1.f, 1.f,
            P, 128, elr, 8, nullptr, nullptr, 0);
        float* Fj = (j == 0) ? F0 : (j == 1) ? F1 : F2;
        gat_gather4<<<(N2 + 3) / 4, 256, 0, stream>>>(csr_all, offs, 3 * N1 + j * N2, N2, elr, P, Fj);
    }
    gemm_bf16<8, 1, 0><<<dim3((N2 + 127) / 128, 2), 256, 0, stream>>>(
        h1, h1, h1, h1, N2, p2L1, 256, feat_b + 128, relWl_b + 128, 128, 0.01f, 1.f,
        F3, 128, glbuf, 128, nullptr, nullptr, 0);
    gemm_bf16<8, 4, 2><<<dim3((N2 * 4 + 127) / 128, 1), 256, 0, stream>>>(
        F0, F1, F2, F3, N2, pF1, 128, relWr_b + 128, nullptr, 128, 1.f, 1.f,
        wbuf, 0, nullptr, 0, glbuf, rela_W + 16, 4);
    gemm_bf16<8, 4, 3><<<dim3((N2 * 4 + 127) / 128, 1), 256, 0, stream>>>(
        F0, F1, F2, F3, N2, pF1 + 16384, 128, relP_b + 128, nullptr, 128, 1.f, 1.f,
        h2, 128, wbuf, 0, nullptr, nullptr, 0);

    // ---- proj + hop gl ----
    gemm_bf16<8, 1, 0><<<dim3((N2 + 127) / 128, 2), 256, 0, stream>>>(
        x, x, x, x, N2, pE, 256, proj_b, hopWl_b, 128, 1.f, 1.f,
        hopp0, 128, glhop, 128, nullptr, nullptr, 0);

    // ---- hop attention over [proj, h1[:N2], h2] (K=3 via dummy 4th plane) ----
    gemm_bf16<8, 4, 2><<<dim3((N2 * 4 + 127) / 128, 1), 256, 0, stream>>>(
        hopp0, h1, h2, hopp0, N2, pG, 128, hopWr_b, nullptr, 128, 1.f, 1.f,
        wbuf, 0, nullptr, 0, glhop, hopa_W, 3);
    gemm_bf16<8, 4, 3><<<dim3((N2 * 4 + 127) / 128, 1), 256, 0, stream>>>(
        hopp0, h1, h2, hopp0, N2, pG + 16384, 128, hopP_b, nullptr, 128, 1.f, 1.f,
        hout, 128, wbuf, 0, nullptr, nullptr, 0);

    // ---- final linear ----
    lin_kernel<<<(N2 * 2 + 255) / 256, 256, 0, stream>>>(hout, lin_W, lin_b, out, N2);
}

// Round 9
// 613.543 us; speedup vs baseline: 4.1646x; 1.0755x over previous
//
#include <hip/hip_runtime.h>

#define N0 100000
#define N1 50000
#define N2 25000
#define E0 500000
#define E1 250000
#define N_TOT (3 * N1 + 3 * N2)
#define NE_ALL (3 * E0 + 3 * E1)
#define BNODE 512
#define NBUCK ((N_TOT + BNODE - 1) / BNODE)   // 440
#define BCAP 12288

typedef __attribute__((ext_vector_type(8))) short short8;
typedef __attribute__((ext_vector_type(4))) float f32x4;
typedef unsigned short ushort_t;
typedef unsigned int uint_t;

static __device__ __forceinline__ float lrelu(float x, float s) {
    return x >= 0.f ? x : s * x;
}

static __device__ __forceinline__ ushort_t f2bf(float f) {
    union { float f; uint_t u; } v; v.f = f;
    uint_t r = v.u + 0x7FFFu + ((v.u >> 16) & 1u);
    return (ushort_t)(r >> 16);
}

static __device__ __forceinline__ float bf_lo(uint_t u) {
    union { uint_t i; float f; } v; v.i = u << 16;
    return v.f;
}
static __device__ __forceinline__ float bf_hi(uint_t u) {
    union { uint_t i; float f; } v; v.i = u & 0xFFFF0000u;
    return v.f;
}

static __device__ __forceinline__ uint_t cvt2(float lo, float hi) {
    uint_t r;
    asm("v_cvt_pk_bf16_f32 %0, %1, %2" : "=v"(r) : "v"(lo), "v"(hi));
    return r;
}

// ================= MFMA GEMM =================
// 256 thr = 4 waves; tile 128 rows x CT*16 cols. A: f32 global (PLANES
// row-interleaved), cvt bf16 in-reg. B: bf16 [col][k] LDS panel (XOR swizzle).
// OUTMODE 0: f32 outputs, GLOBAL col < colsplit -> O1 else O2 (LDS transpose).
// OUTMODE 1 (conv): col<128 -> bf16 O1 (P), col>=128 -> f32 O2 (elr, ld2=8).
// OUTMODE 4 (fused gated attention): PLANES=4, 2 B-panels [Wr|Wp].
//   Epilogue per 16-row pass: z=gr+br transpose -> e=dot(lrelu(z+gl),aW)
//   (no shuffles) -> softmax over k in LDS -> v=accV+bp transpose ->
//   h[node]=lrelu(sum_k w*v,0.01) -> O1. gl from glp; kreal masks dummy k.
template <int CT, int PLANES, int OUTMODE>
__global__ __launch_bounds__(256) void gemm_bf16(
    const float* __restrict__ A0, const float* __restrict__ A1,
    const float* __restrict__ A2, const float* __restrict__ A3,
    int nodes, const ushort_t* __restrict__ Bt, int cols,
    const float* __restrict__ biasA, const float* __restrict__ biasB,
    int colsplit, float slopeA, float slopeB,
    void* __restrict__ O1, int ld1, float* __restrict__ O2, int ld2,
    const float* __restrict__ glp, const float* __restrict__ aWp, int kreal)
{
    constexpr int BCOLS = CT * 16;
    constexpr int NPANEL = (OUTMODE == 4) ? 2 : 1;
    constexpr int SCOLS = BCOLS * NPANEL;
    constexpr int CSTR = BCOLS + 4;
    constexpr int SH_B = SCOLS * 256;
    constexpr int SH_C = 64 * CSTR * 4 + ((OUTMODE == 4) ? 4096 : 0);
    constexpr int SHSZ = SH_B > SH_C ? SH_B : SH_C;
    __shared__ char sh[SHSZ];
    float* Cs = (float*)sh;

    const int Mrows = nodes * PLANES;
    const int row0 = blockIdx.x * 128;
    const int cbase = blockIdx.y * BCOLS;
    const int tid = threadIdx.x;

    // ---- stage B panel(s) (swizzled) ----
    for (int u = tid; u < SCOLS * 16; u += 256) {
        int cl = u >> 4;
        int q = u & 15;
        int off = cl * 256 + q * 16;
        off ^= (cl & 7) << 4;
        int c = cbase + cl;   // for OUTMODE 4: cbase=0, cl spans both panels
        uint4 d = make_uint4(0, 0, 0, 0);
        if (c < cols) d = *(const uint4*)(Bt + (size_t)c * 128 + q * 8);
        *(uint4*)(sh + off) = d;
    }
    __syncthreads();

    const int wv = tid >> 6;
    const int l = tid & 63;
    const int kg = l >> 4;
    const float* aptr[2];
    #pragma unroll
    for (int rt = 0; rt < 2; ++rt) {
        int rg = row0 + wv * 32 + rt * 16 + (l & 15);
        if (rg >= Mrows) rg = Mrows - 1;
        int node, pl;
        if (PLANES == 1) { node = rg; pl = 0; }
        else { node = rg / PLANES; pl = rg % PLANES; }
        const float* base = (pl == 0) ? A0 : (pl == 1) ? A1 : (pl == 2) ? A2 : A3;
        aptr[rt] = base + (size_t)node * 128 + kg * 8;
    }

    f32x4 acc[2][CT];
    f32x4 accV[2][(OUTMODE == 4) ? CT : 1];
    #pragma unroll
    for (int a = 0; a < 2; ++a) {
        #pragma unroll
        for (int b = 0; b < CT; ++b)
            #pragma unroll
            for (int q = 0; q < 4; ++q) acc[a][b][q] = 0.f;
        if (OUTMODE == 4)
            #pragma unroll
            for (int b = 0; b < CT; ++b)
                #pragma unroll
                for (int q = 0; q < 4; ++q) accV[a][b][q] = 0.f;
    }

    #pragma unroll
    for (int kt = 0; kt < 4; ++kt) {
        short8 af[2];
        #pragma unroll
        for (int rt = 0; rt < 2; ++rt) {
            const float4* p = (const float4*)(aptr[rt] + kt * 32);
            float4 x0 = p[0];
            float4 x1 = p[1];
            union { uint_t u[4]; short8 s; } u;
            u.u[0] = cvt2(x0.x, x0.y);
            u.u[1] = cvt2(x0.z, x0.w);
            u.u[2] = cvt2(x1.x, x1.y);
            u.u[3] = cvt2(x1.z, x1.w);
            af[rt] = u.s;
        }
        #pragma unroll
        for (int ct = 0; ct < CT; ++ct) {
            int off = ((ct * 16 + (l & 15)) * 256) + kt * 64 + (l >> 4) * 16;
            off ^= (l & 7) << 4;
            short8 bfr = *(const short8*)(sh + off);
            acc[0][ct] = __builtin_amdgcn_mfma_f32_16x16x32_bf16(af[0], bfr, acc[0][ct], 0, 0, 0);
            acc[1][ct] = __builtin_amdgcn_mfma_f32_16x16x32_bf16(af[1], bfr, acc[1][ct], 0, 0, 0);
            if (OUTMODE == 4) {
                int offv = ((128 + ct * 16 + (l & 15)) * 256) + kt * 64 + (l >> 4) * 16;
                offv ^= (l & 7) << 4;
                short8 bfv = *(const short8*)(sh + offv);
                accV[0][ct] = __builtin_amdgcn_mfma_f32_16x16x32_bf16(af[0], bfv, accV[0][ct], 0, 0, 0);
                accV[1][ct] = __builtin_amdgcn_mfma_f32_16x16x32_bf16(af[1], bfv, accV[1][ct], 0, 0, 0);
            }
        }
    }

    if (OUTMODE == 4) {
        const int node0 = row0 >> 2;
        float* e_sh = (float*)(sh + 64 * CSTR * 4);
        float* w_sh = e_sh + 512;
        float4 aw0 = ((const float4*)aWp)[0];
        float4 aw1 = ((const float4*)aWp)[1];
        float4 aw2 = ((const float4*)aWp)[2];
        float4 aw3 = ((const float4*)aWp)[3];
        #pragma unroll
        for (int rt = 0; rt < 2; ++rt) {
            __syncthreads();   // B reads done / prior-pass Cs reads done
            // z = gr + br, transposed into Cs
            #pragma unroll
            for (int ct = 0; ct < CT; ++ct) {
                int col = ct * 16 + (l & 15);
                float br_ = biasA[col];
                int lrow = wv * 16 + (l >> 4) * 4;
                #pragma unroll
                for (int j = 0; j < 4; ++j)
                    Cs[(lrow + j) * CSTR + col] = acc[rt][ct][j] + br_;
            }
            __syncthreads();
            // e-pass: 2 (row,head) pairs per thread; contiguous float4 reads
            #pragma unroll
            for (int i = 0; i < 2; ++i) {
                int p = tid + i * 256;
                int row = p >> 3, head = p & 7;
                int rg = row0 + rt * 16 + ((row >> 4) << 5) + (row & 15);
                int node = rg >> 2;
                if (node > nodes - 1) node = nodes - 1;
                const float* zr = &Cs[row * CSTR + head * 16];
                const float* glr = glp + (size_t)node * 128 + head * 16;
                float4 c0 = *(const float4*)(zr);
                float4 c1 = *(const float4*)(zr + 4);
                float4 c2 = *(const float4*)(zr + 8);
                float4 c3 = *(const float4*)(zr + 12);
                float4 g0 = *(const float4*)(glr);
                float4 g1 = *(const float4*)(glr + 4);
                float4 g2 = *(const float4*)(glr + 8);
                float4 g3 = *(const float4*)(glr + 12);
                float e =
                    lrelu(c0.x + g0.x, 0.01f) * aw0.x + lrelu(c0.y + g0.y, 0.01f) * aw0.y +
                    lrelu(c0.z + g0.z, 0.01f) * aw0.z + lrelu(c0.w + g0.w, 0.01f) * aw0.w +
                    lrelu(c1.x + g1.x, 0.01f) * aw1.x + lrelu(c1.y + g1.y, 0.01f) * aw1.y +
                    lrelu(c1.z + g1.z, 0.01f) * aw1.z + lrelu(c1.w + g1.w, 0.01f) * aw1.w +
                    lrelu(c2.x + g2.x, 0.01f) * aw2.x + lrelu(c2.y + g2.y, 0.01f) * aw2.y +
                    lrelu(c2.z + g2.z, 0.01f) * aw2.z + lrelu(c2.w + g2.w, 0.01f) * aw2.w +
                    lrelu(c3.x + g3.x, 0.01f) * aw3.x + lrelu(c3.y + g3.y, 0.01f) * aw3.y +
                    lrelu(c3.z + g3.z, 0.01f) * aw3.z + lrelu(c3.w + g3.w, 0.01f) * aw3.w;
                e_sh[row * 8 + head] = e;
            }
            __syncthreads();
            // softmax over k (per node, head)
            if (tid < 128) {
                int q = tid >> 3, head = tid & 7;
                int rho0 = (q >> 2) * 16 + (q & 3) * 4;
                float e0 = e_sh[(rho0 + 0) * 8 + head];
                float e1 = e_sh[(rho0 + 1) * 8 + head];
                float e2 = e_sh[(rho0 + 2) * 8 + head];
                float e3 = (kreal == 4) ? e_sh[(rho0 + 3) * 8 + head] : -1e30f;
                float m = fmaxf(fmaxf(e0, e1), fmaxf(e2, e3));
                float x0 = __expf(e0 - m), x1 = __expf(e1 - m), x2 = __expf(e2 - m);
                float x3 = (kreal == 4) ? __expf(e3 - m) : 0.f;
                float inv = 1.f / (x0 + x1 + x2 + x3);
                w_sh[q * 32 + 0 + head] = x0 * inv;
                w_sh[q * 32 + 8 + head] = x1 * inv;
                w_sh[q * 32 + 16 + head] = x2 * inv;
                w_sh[q * 32 + 24 + head] = x3 * inv;
            }
            __syncthreads();
            // v = accV + bp, transposed into Cs (overwrites z)
            #pragma unroll
            for (int ct = 0; ct < CT; ++ct) {
                int col = ct * 16 + (l & 15);
                float bp_ = biasB[col];
                int lrow = wv * 16 + (l >> 4) * 4;
                #pragma unroll
                for (int j = 0; j < 4; ++j)
                    Cs[(lrow + j) * CSTR + col] = accV[rt][ct][j] + bp_;
            }
            __syncthreads();
            // combine: h[node] = lrelu(sum_k w*v, 0.01)
            #pragma unroll
            for (int it = tid; it < 512; it += 256) {
                int nidx = it >> 5;
                int c4 = it & 31;
                int nl = rt * 4 + (nidx >> 2) * 8 + (nidx & 3);
                int gn = node0 + nl;
                if (gn >= nodes) continue;
                int head = c4 >> 2;
                float4 o = make_float4(0.f, 0.f, 0.f, 0.f);
                #pragma unroll
                for (int k = 0; k < 4; ++k) {
                    int lr = 4 * nl + k;
                    int rho = ((lr >> 5) << 4) | (lr & 15);
                    float wk = w_sh[nidx * 32 + k * 8 + head];
                    float4 v4 = *(const float4*)&Cs[rho * CSTR + c4 * 4];
                    o.x += wk * v4.x; o.y += wk * v4.y;
                    o.z += wk * v4.z; o.w += wk * v4.w;
                }
                o.x = lrelu(o.x, 0.01f); o.y = lrelu(o.y, 0.01f);
                o.z = lrelu(o.z, 0.01f); o.w = lrelu(o.w, 0.01f);
                *(float4*)((float*)O1 + (size_t)gn * 128 + c4 * 4) = o;
            }
        }
        return;
    }

    // ---- OUTMODE 0/1: LDS transpose, clean vector stores ----
    #pragma unroll
    for (int rt = 0; rt < 2; ++rt) {
        __syncthreads();
        #pragma unroll
        for (int ct = 0; ct < CT; ++ct) {
            int c = cbase + ct * 16 + (l & 15);
            float bias_ = 0.f, slope_ = 1.f;
            if (c < colsplit) {
                if (biasA) bias_ = biasA[c];
                slope_ = slopeA;
            } else if (c < cols) {
                if (biasB) bias_ = biasB[c - colsplit];
                slope_ = slopeB;
            }
            int lrow = wv * 16 + (l >> 4) * 4;
            #pragma unroll
            for (int j = 0; j < 4; ++j) {
                float v = acc[rt][ct][j] + bias_;
                v = v >= 0.f ? v : v * slope_;
                Cs[(lrow + j) * CSTR + ct * 16 + (l & 15)] = v;
            }
        }
        __syncthreads();
        for (int i = tid; i < 64 * CT * 4; i += 256) {
            int rho = i / (CT * 4);
            int c4 = i - rho * (CT * 4);
            int col = c4 * 4;
            int gcol = cbase + col;
            int rg = row0 + rt * 16 + (rho >> 4) * 32 + (rho & 15);
            if (rg >= Mrows || gcol >= cols) continue;
            float4 v = *(const float4*)&Cs[rho * CSTR + col];
            if (OUTMODE == 1) {
                if (gcol < 128) {
                    uint2 pk;
                    pk.x = cvt2(v.x, v.y);
                    pk.y = cvt2(v.z, v.w);
                    *(uint2*)((ushort_t*)O1 + (size_t)rg * ld1 + gcol) = pk;
                } else {
                    *(float4*)(O2 + (size_t)rg * ld2 + (gcol - 128)) = v;
                }
            } else {
                if (gcol < colsplit)
                    *(float4*)((float*)O1 + (size_t)rg * ld1 + gcol) = v;
                else
                    *(float4*)(O2 + (size_t)rg * ld2 + (gcol - colsplit)) = v;
            }
        }
    }
}

// ================= weight prep =================
__global__ __launch_bounds__(128) void prep2(
    const float* __restrict__ Wa, const float* __restrict__ Wb, ushort_t* __restrict__ dst)
{
    int c = blockIdx.x, k = threadIdx.x;
    const float* W = (c < 128) ? Wa : Wb;
    int cc = c & 127;
    dst[c * 128 + k] = f2bf(W[k * 128 + cc]);
}

__global__ __launch_bounds__(128) void prep_conv(
    const float* __restrict__ W, const float* __restrict__ al, const float* __restrict__ ar,
    ushort_t* __restrict__ dst)
{
    int c = blockIdx.x, k = threadIdx.x;
    float v;
    if (c < 128) {
        v = W[k * 128 + c];
    } else {
        int idx = c - 128;
        int g = idx & 3;
        const float* a = (idx < 4) ? al : ar;
        float s = 0.f;
        for (int d = 0; d < 32; ++d) s += W[k * 128 + g * 32 + d] * a[g * 32 + d];
        v = s;
    }
    dst[c * 128 + k] = f2bf(v);
}

// ================= binned CSR build =================
static __device__ __forceinline__ void edge_decode(
    int idx, const int* __restrict__ src0, const int* __restrict__ dst0,
    const int* __restrict__ src1, const int* __restrict__ dst1,
    int& src, int& gnode)
{
    if (idx < 3 * E0) {
        src = src0[idx];
        gnode = (idx / E0) * N1 + dst0[idx];
    } else {
        int k = idx - 3 * E0;
        src = src1[k];
        gnode = 3 * N1 + (k / E1) * N2 + dst1[k];
    }
}

__global__ __launch_bounds__(256) void bin_pass(
    const int* __restrict__ src0, const int* __restrict__ dst0,
    const int* __restrict__ src1, const int* __restrict__ dst1,
    int* __restrict__ bcur, uint_t* __restrict__ tmp)
{
    __shared__ int lcnt[512];
    __shared__ int lbase[512];
    const int tid = threadIdx.x;
    const int e0 = blockIdx.x * 4096;
    for (int t = tid; t < 512; t += 256) lcnt[t] = 0;
    __syncthreads();
    #pragma unroll
    for (int i = 0; i < 16; ++i) {
        int idx = e0 + i * 256 + tid;
        if (idx < NE_ALL) {
            int s, g;
            edge_decode(idx, src0, dst0, src1, dst1, s, g);
            atomicAdd(&lcnt[g >> 9], 1);
        }
    }
    __syncthreads();
    for (int t = tid; t < 512; t += 256) {
        int c = lcnt[t];
        lbase[t] = c ? atomicAdd(&bcur[t], c) : 0;
        lcnt[t] = 0;
    }
    __syncthreads();
    #pragma unroll
    for (int i = 0; i < 16; ++i) {
        int idx = e0 + i * 256 + tid;
        if (idx < NE_ALL) {
            int s, g;
            edge_decode(idx, src0, dst0, src1, dst1, s, g);
            int b = g >> 9;
            int p = lbase[b] + atomicAdd(&lcnt[b], 1);
            if (p < BCAP)
                tmp[(size_t)b * BCAP + p] = (uint_t)((s << 9) | (g & 511));
        }
    }
}

__global__ __launch_bounds__(512) void bucket_scan(
    const int* __restrict__ bcur, int* __restrict__ bbase)
{
    __shared__ int s[512];
    int t = threadIdx.x;
    int v = (t < NBUCK) ? bcur[t] : 0;
    s[t] = v;
    __syncthreads();
    for (int off = 1; off < 512; off <<= 1) {
        int x = (t >= off) ? s[t - off] : 0;
        __syncthreads();
        s[t] += x;
        __syncthreads();
    }
    bbase[t] = s[t] - v;
}

__global__ __launch_bounds__(256) void build_pass(
    const int* __restrict__ bcur, const int* __restrict__ bbase,
    const uint_t* __restrict__ tmp, int* __restrict__ offs, int* __restrict__ csr)
{
    __shared__ int cnt[512];
    __shared__ int offl[512];
    __shared__ int ps[256];
    const int tid = threadIdx.x;
    const int b = blockIdx.x;
    int nE = bcur[b];
    if (nE > BCAP) nE = BCAP;
    const int base = bbase[b];
    const int node0 = b * BNODE;
    const uint_t* tp = tmp + (size_t)b * BCAP;

    for (int t = tid; t < 512; t += 256) cnt[t] = 0;
    __syncthreads();
    for (int i = tid; i < nE; i += 256)
        atomicAdd(&cnt[tp[i] & 511], 1);
    __syncthreads();
    int a0 = cnt[2 * tid], a1 = cnt[2 * tid + 1];
    ps[tid] = a0 + a1;
    __syncthreads();
    for (int off = 1; off < 256; off <<= 1) {
        int x = (tid >= off) ? ps[tid - off] : 0;
        __syncthreads();
        ps[tid] += x;
        __syncthreads();
    }
    int ex = ps[tid] - (a0 + a1);
    offl[2 * tid] = ex;
    offl[2 * tid + 1] = ex + a0;
    __syncthreads();
    for (int t = tid; t < BNODE; t += 256) {
        int gn = node0 + t;
        if (gn < N_TOT) offs[gn] = base + offl[t];
    }
    if (b == NBUCK - 1 && tid == 0) offs[N_TOT] = base + nE;
    for (int t = tid; t < 512; t += 256) cnt[t] = 0;
    __syncthreads();
    for (int i = tid; i < nE; i += 256) {
        uint_t pk = tp[i];
        int ld = pk & 511;
        int p = atomicAdd(&cnt[ld], 1);
        csr[base + offl[ld] + p] = (int)(pk >> 9);
    }
}

// ====== softmax gather: one WAVE per node, 4 slots x 16 lanes, no LDS ======
__global__ __launch_bounds__(256) void gat_gather4(
    const int* __restrict__ csrc, const int* __restrict__ offs, int nodeBase,
    int nNodes, const float* __restrict__ elr, const ushort_t* __restrict__ P,
    float* __restrict__ out)
{
    const int wv = threadIdx.x >> 6;
    const int node = blockIdx.x * 4 + wv;
    if (node >= nNodes) return;
    const int l = threadIdx.x & 63;
    const int lane16 = l & 15;
    const int slot = l >> 4;
    const int g = lane16 >> 2;
    const int beg = offs[nodeBase + node], end = offs[nodeBase + node + 1];
    const float erg = elr[(size_t)node * 8 + 4 + g];
    float den = 0.f;
    float a0 = 0.f, a1 = 0.f, a2 = 0.f, a3 = 0.f;
    float a4 = 0.f, a5 = 0.f, a6 = 0.f, a7 = 0.f;
    for (int i = beg + slot; i < end; i += 4) {
        int s = csrc[i];
        float w = __expf(lrelu(elr[(size_t)s * 8 + g] + erg, 0.2f));
        uint4 d = *(const uint4*)(P + (size_t)s * 128 + lane16 * 8);
        den += w;
        a0 += w * bf_lo(d.x); a1 += w * bf_hi(d.x);
        a2 += w * bf_lo(d.y); a3 += w * bf_hi(d.y);
        a4 += w * bf_lo(d.z); a5 += w * bf_hi(d.z);
        a6 += w * bf_lo(d.w); a7 += w * bf_hi(d.w);
    }
    #pragma unroll
    for (int m = 16; m <= 32; m <<= 1) {
        den += __shfl_xor(den, m);
        a0 += __shfl_xor(a0, m); a1 += __shfl_xor(a1, m);
        a2 += __shfl_xor(a2, m); a3 += __shfl_xor(a3, m);
        a4 += __shfl_xor(a4, m); a5 += __shfl_xor(a5, m);
        a6 += __shfl_xor(a6, m); a7 += __shfl_xor(a7, m);
    }
    if (slot == 0) {
        float inv = (end > beg) ? 1.f / den : 0.f;
        float4 o0, o1;
        o0.x = lrelu(a0 * inv, 0.01f); o0.y = lrelu(a1 * inv, 0.01f);
        o0.z = lrelu(a2 * inv, 0.01f); o0.w = lrelu(a3 * inv, 0.01f);
        o1.x = lrelu(a4 * inv, 0.01f); o1.y = lrelu(a5 * inv, 0.01f);
        o1.z = lrelu(a6 * inv, 0.01f); o1.w = lrelu(a7 * inv, 0.01f);
        float* op = out + (size_t)node * 128 + lane16 * 8;
        *(float4*)op = o0;
        *(float4*)(op + 4) = o1;
    }
}

// ================= final linear 128 -> 2 =================
__global__ __launch_bounds__(256) void lin_kernel(
    const float* __restrict__ H, const float* __restrict__ W,
    const float* __restrict__ b, float* __restrict__ out, int n)
{
    int idx = blockIdx.x * 256 + threadIdx.x;
    int node = idx >> 1, c = idx & 1;
    if (node >= n) return;
    float acc = 0.f;
    for (int k = 0; k < 128; ++k)
        acc += H[(size_t)node * 128 + k] * W[k * 2 + c];
    out[(size_t)node * 2 + c] = acc + b[c];
}

extern "C" void kernel_launch(void* const* d_in, const int* in_sizes, int n_in,
                              void* d_out, int out_size, void* d_ws, size_t ws_size,
                              hipStream_t stream)
{
    (void)in_sizes; (void)n_in; (void)out_size; (void)ws_size;
    const float* x       = (const float*)d_in[0];
    const int*   src0    = (const int*)d_in[1];
    const int*   dst0    = (const int*)d_in[2];
    const int*   src1    = (const int*)d_in[3];
    const int*   dst1    = (const int*)d_in[4];
    const float* conv_W  = (const float*)d_in[5];
    const float* conv_al = (const float*)d_in[6];
    const float* conv_ar = (const float*)d_in[7];
    const float* feat_W  = (const float*)d_in[8];
    const float* feat_b  = (const float*)d_in[9];
    const float* relWl_W = (const float*)d_in[10];
    const float* relWl_b = (const float*)d_in[11];
    const float* relWr_W = (const float*)d_in[12];
    const float* relWr_b = (const float*)d_in[13];
    const float* relP_W  = (const float*)d_in[14];
    const float* relP_b  = (const float*)d_in[15];
    const float* rela_W  = (const float*)d_in[16];
    const float* proj_W  = (const float*)d_in[18];
    const float* proj_b  = (const float*)d_in[19];
    const float* hopWl_W = (const float*)d_in[20];
    const float* hopWl_b = (const float*)d_in[21];
    const float* hopWr_W = (const float*)d_in[22];
    const float* hopWr_b = (const float*)d_in[23];
    const float* hopP_W  = (const float*)d_in[24];
    const float* hopP_b  = (const float*)d_in[25];
    const float* hopa_W  = (const float*)d_in[26];
    const float* lin_W   = (const float*)d_in[28];
    const float* lin_b   = (const float*)d_in[29];
    float* out = (float*)d_out;

    // ---- workspace layout (~206 MB) ----
    char* base = (char*)d_ws;
    size_t off = 0;
    auto alloc = [&](size_t bytes) -> void* {
        void* p = base + off;
        off += (bytes + 255) & ~(size_t)255;
        return p;
    };
    ushort_t* P     = (ushort_t*)alloc((size_t)N0 * 128 * 2);
    float* elr      = (float*)alloc((size_t)N0 * 8 * 4);
    float* F0       = (float*)alloc((size_t)N1 * 128 * 4);
    float* F1       = (float*)alloc((size_t)N1 * 128 * 4);
    float* F2       = (float*)alloc((size_t)N1 * 128 * 4);
    float* F3       = (float*)alloc((size_t)N1 * 128 * 4);
    float* glbuf    = (float*)alloc((size_t)N1 * 128 * 4);
    float* h1       = (float*)alloc((size_t)N1 * 128 * 4);
    float* glhop    = (float*)alloc((size_t)N2 * 128 * 4);
    int*   csr_all  = (int*)alloc((size_t)NE_ALL * 4);
    int*   offs     = (int*)alloc((size_t)(N_TOT + 1) * 4);
    int*   bcur     = (int*)alloc(512 * 4);
    int*   bbase    = (int*)alloc(512 * 4);
    ushort_t* pconv[6];
    for (int i = 0; i < 6; ++i) pconv[i] = (ushort_t*)alloc(136 * 128 * 2);
    ushort_t* p2L0 = (ushort_t*)alloc(256 * 128 * 2);
    ushort_t* p2L1 = (ushort_t*)alloc(256 * 128 * 2);
    ushort_t* pE   = (ushort_t*)alloc(256 * 128 * 2);
    ushort_t* pF0  = (ushort_t*)alloc(256 * 128 * 2);
    ushort_t* pF1  = (ushort_t*)alloc(256 * 128 * 2);
    ushort_t* pG   = (ushort_t*)alloc(256 * 128 * 2);

    float* h2    = F1;          // written block-locally after L1 attn reads
    float* hopp0 = F0;          // proj plane, after L1 attn done
    float* hout  = glbuf;       // glbuf (rel gl) dead by hop combine
    uint_t* tmp  = (uint_t*)F0; // 21.6 MB bin arenas; CSR build precedes F writes

    // ---- weight prep ----
    for (int i = 0; i < 6; ++i)
        prep_conv<<<136, 128, 0, stream>>>(conv_W + (size_t)i * 16384,
                                           conv_al + (size_t)i * 128,
                                           conv_ar + (size_t)i * 128, pconv[i]);
    prep2<<<256, 128, 0, stream>>>(feat_W, relWl_W, p2L0);
    prep2<<<256, 128, 0, stream>>>(feat_W + 16384, relWl_W + 16384, p2L1);
    prep2<<<256, 128, 0, stream>>>(proj_W, hopWl_W, pE);
    prep2<<<256, 128, 0, stream>>>(relWr_W, relP_W, pF0);
    prep2<<<256, 128, 0, stream>>>(relWr_W + 16384, relP_W + 16384, pF1);
    prep2<<<256, 128, 0, stream>>>(hopWr_W, hopP_W, pG);

    // ---- binned CSR build ----
    hipMemsetAsync(bcur, 0, 512 * 4, stream);
    bin_pass<<<(NE_ALL + 4095) / 4096, 256, 0, stream>>>(src0, dst0, src1, dst1, bcur, tmp);
    bucket_scan<<<1, 512, 0, stream>>>(bcur, bbase);
    build_pass<<<NBUCK, 256, 0, stream>>>(bcur, bbase, tmp, offs, csr_all);

    // ---- layer 0 ----
    for (int j = 0; j < 3; ++j) {
        gemm_bf16<9, 1, 1><<<dim3((N0 + 127) / 128, 1), 256, 0, stream>>>(
            x, x, x, x, N0, pconv[j], 136, nullptr, nullptr, 128, 1.f, 1.f,
            P, 128, elr, 8, nullptr, nullptr, 0);
        float* Fj = (j == 0) ? F0 : (j == 1) ? F1 : F2;
        gat_gather4<<<(N1 + 3) / 4, 256, 0, stream>>>(csr_all, offs, j * N1, N1, elr, P, Fj);
    }
    gemm_bf16<8, 1, 0><<<dim3((N1 + 127) / 128, 2), 256, 0, stream>>>(
        x, x, x, x, N1, p2L0, 256, feat_b, relWl_b, 128, 0.01f, 1.f,
        F3, 128, glbuf, 128, nullptr, nullptr, 0);
    gemm_bf16<8, 4, 4><<<dim3((N1 * 4 + 127) / 128, 1), 256, 0, stream>>>(
        F0, F1, F2, F3, N1, pF0, 256, relWr_b, relP_b, 128, 1.f, 1.f,
        h1, 128, nullptr, 0, glbuf, rela_W, 4);

    // ---- layer 1 ----
    for (int j = 0; j < 3; ++j) {
        gemm_bf16<9, 1, 1><<<dim3((N1 + 127) / 128, 1), 256, 0, stream>>>(
            h1, h1, h1, h1, N1, pconv[3 + j], 136, nullptr, nullptr, 128, 1.f, 1.f,
            P, 128, elr, 8, nullptr, nullptr, 0);
        float* Fj = (j == 0) ? F0 : (j == 1) ? F1 : F2;
        gat_gather4<<<(N2 + 3) / 4, 256, 0, stream>>>(csr_all, offs, 3 * N1 + j * N2, N2, elr, P, Fj);
    }
    gemm_bf16<8, 1, 0><<<dim3((N2 + 127) / 128, 2), 256, 0, stream>>>(
        h1, h1, h1, h1, N2, p2L1, 256, feat_b + 128, relWl_b + 128, 128, 0.01f, 1.f,
        F3, 128, glbuf, 128, nullptr, nullptr, 0);
    gemm_bf16<8, 4, 4><<<dim3((N2 * 4 + 127) / 128, 1), 256, 0, stream>>>(
        F0, F1, F2, F3, N2, pF1, 256, relWr_b + 128, relP_b + 128, 128, 1.f, 1.f,
        h2, 128, nullptr, 0, glbuf, rela_W + 16, 4);

    // ---- proj + hop gl ----
    gemm_bf16<8, 1, 0><<<dim3((N2 + 127) / 128, 2), 256, 0, stream>>>(
        x, x, x, x, N2, pE, 256, proj_b, hopWl_b, 128, 1.f, 1.f,
        hopp0, 128, glhop, 128, nullptr, nullptr, 0);

    // ---- hop attention over [proj, h1[:N2], h2] (K=3 via dummy 4th plane) ----
    gemm_bf16<8, 4, 4><<<dim3((N2 * 4 + 127) / 128, 1), 256, 0, stream>>>(
        hopp0, h1, h2, hopp0, N2, pG, 256, hopWr_b, hopP_b, 128, 1.f, 1.f,
        hout, 128, nullptr, 0, glhop, hopa_W, 3);

    // ---- final linear ----
    lin_kernel<<<(N2 * 2 + 255) / 256, 256, 0, stream>>>(hout, lin_W, lin_b, out, N2);
}